// Round 2
// baseline (398.378 us; speedup 1.0000x reference)
//
#include <hip/hip_runtime.h>

// Problem constants (fixed by reference)
#define B_ROWS 8192
#define E_DIM  256
#define H_DIM  4096

typedef __attribute__((ext_vector_type(8))) short short8;
typedef __attribute__((ext_vector_type(4))) float f32x4;

typedef __attribute__((address_space(1))) const void* gas1_t;
typedef __attribute__((address_space(3))) void*       las3_t;

__device__ __forceinline__ float b2f(unsigned short s) {
    return __uint_as_float(((unsigned)s) << 16);
}
__device__ __forceinline__ unsigned short f2b(float f) {
    unsigned u = __float_as_uint(f);
    u += 0x7fffu + ((u >> 16) & 1u);   // RNE
    return (unsigned short)(u >> 16);
}

// HW packed f32->bf16 convert (1 instr for 2 elements vs 4 VALU ops each).
// GEMM2 A-path only; verified absmax-neutral (7.6e-6) in R16.
__device__ __forceinline__ unsigned cvt_pk_bf16(float lo, float hi) {
    unsigned r;
    asm("v_cvt_pk_bf16_f32 %0, %1, %2" : "=v"(r) : "v"(lo), "v"(hi));
    return r;
}

// LDS swizzle for BK=32 (64B rows, 4x16B slots): slot' = slot ^ ((row>>1)&3)
// -> ds_read_b128 fragment reads are 2-way (free, m136) instead of 8-way.
__device__ __forceinline__ int swz(int row, int slot) {
    return slot ^ ((row >> 1) & 3);
}

// ---------------------------------------------------------------------------
// Transpose + cast f32 [R,C] -> bf16 [C,R]
__global__ void k_transpose_cast(const float* __restrict__ in,
                                 unsigned short* __restrict__ out,
                                 int R, int C) {
    __shared__ float tile[32][33];
    const int c0 = blockIdx.x * 32, r0 = blockIdx.y * 32;
    const int tx = threadIdx.x & 31, ty = threadIdx.x >> 5;  // ty 0..7
#pragma unroll
    for (int j = 0; j < 4; ++j)
        tile[ty * 4 + j][tx] = in[(size_t)(r0 + ty * 4 + j) * C + c0 + tx];
    __syncthreads();
#pragma unroll
    for (int j = 0; j < 4; ++j)
        out[(size_t)(c0 + ty * 4 + j) * R + r0 + tx] = f2b(tile[tx][ty * 4 + j]);
}

// ---------------------------------------------------------------------------
// Cast f32 -> bf16, 4 elems/thread.
__global__ void k_cast_bf16(const float* __restrict__ in,
                            unsigned short* __restrict__ out, int n4) {
    int i = blockIdx.x * blockDim.x + threadIdx.x;
    if (i < n4) {
        float4 v = ((const float4*)in)[i];
        ushort4 o;
        o.x = f2b(v.x); o.y = f2b(v.y); o.z = f2b(v.z); o.w = f2b(v.w);
        ((ushort4*)out)[i] = o;
    }
}

// ---------------------------------------------------------------------------
// GEMM1 (R10 proven): h[M,N] = A[M,K] * Bt[N,K]^T, bf16 out + fused col stats.
// BM=BN=128, BK=32, swizzled global_load_lds staging. grid (N/128, M/128).
__global__ __launch_bounds__(256) void k_gemm1(
    const unsigned short* __restrict__ A, const unsigned short* __restrict__ Bt,
    unsigned short* __restrict__ Cout,
    float* __restrict__ cs, float* __restrict__ cs2,
    int M, int N, int K) {
    constexpr int BK = 32, BM = 128, BN = 128;
    constexpr int MI = 4, NI = 4;
    __shared__ __align__(16) short As[BM * BK];
    __shared__ __align__(16) short Bs[BN * BK];

    const int t = threadIdx.x;
    const int lane = t & 63, wv = t >> 6;
    const int wr = wv >> 1, wc = wv & 1;
    const int l15 = lane & 15, quad = lane >> 4;
    const int m0 = blockIdx.y * BM, n0 = blockIdx.x * BN;

    f32x4 acc[MI][NI] = {};

    for (int k0 = 0; k0 < K; k0 += BK) {
#pragma unroll
        for (int q = 0; q < 2; ++q) {
            int u = q * 256 + t;
            int row = u >> 2, kc = swz(row, u & 3);
            const short* gp = (const short*)A + (size_t)(m0 + row) * K + k0 + kc * 8;
            short* lp = As + (size_t)(q * 256 + (wv << 6)) * 8;  // wave-uniform base
            __builtin_amdgcn_global_load_lds((gas1_t)gp, (las3_t)lp, 16, 0, 0);
        }
#pragma unroll
        for (int q = 0; q < 2; ++q) {
            int u = q * 256 + t;
            int row = u >> 2, kc = swz(row, u & 3);
            const short* gp = (const short*)Bt + (size_t)(n0 + row) * K + k0 + kc * 8;
            short* lp = Bs + (size_t)(q * 256 + (wv << 6)) * 8;
            __builtin_amdgcn_global_load_lds((gas1_t)gp, (las3_t)lp, 16, 0, 0);
        }
        __syncthreads();

        short8 af[MI], bfr[NI];
#pragma unroll
        for (int mi = 0; mi < MI; ++mi) {
            int row = wr * 64 + mi * 16 + l15;
            af[mi] = *(const short8*)(As + row * BK + (swz(row, quad) << 3));
        }
#pragma unroll
        for (int ni = 0; ni < NI; ++ni) {
            int row = wc * 64 + ni * 16 + l15;
            bfr[ni] = *(const short8*)(Bs + row * BK + (swz(row, quad) << 3));
        }
#pragma unroll
        for (int mi = 0; mi < MI; ++mi)
#pragma unroll
            for (int ni = 0; ni < NI; ++ni)
                acc[mi][ni] = __builtin_amdgcn_mfma_f32_16x16x32_bf16(
                    af[mi], bfr[ni], acc[mi][ni], 0, 0, 0);
        __syncthreads();
    }

    // epilogue: C/D layout col=lane&15, row=quad*4+reg (measured m89)
#pragma unroll
    for (int ni = 0; ni < NI; ++ni) {
        float s = 0.f, s2 = 0.f;
#pragma unroll
        for (int mi = 0; mi < MI; ++mi)
#pragma unroll
            for (int r = 0; r < 4; ++r) {
                int row = m0 + wr * 64 + mi * 16 + quad * 4 + r;
                int col = n0 + wc * 64 + ni * 16 + l15;
                float v = acc[mi][ni][r];
                Cout[(size_t)row * N + col] = f2b(v);
                s += v; s2 += v * v;
            }
        s  += __shfl_xor(s, 16);  s  += __shfl_xor(s, 32);
        s2 += __shfl_xor(s2, 16); s2 += __shfl_xor(s2, 32);
        if (quad == 0) {
            int col = n0 + wc * 64 + ni * 16 + l15;
            atomicAdd(&cs[col], s);
            atomicAdd(&cs2[col], s2);
        }
    }
}

// BN scale/shift packed as bf16 pair: ssb[k] = f2b(scale)<<16 | f2b(shift)
// (bf16 params verified numerically R6/R9/R10/R14: absmax 7.6e-6 vs 2e-5 thr)
__global__ void k_bnprep(const float* __restrict__ sum, const float* __restrict__ sumsq,
                         const float* __restrict__ gamma, const float* __restrict__ beta,
                         unsigned* __restrict__ ssb) {
    int j = blockIdx.x * 256 + threadIdx.x;
    float mu = sum[j] * (1.f / B_ROWS);
    float var = sumsq[j] * (1.f / B_ROWS) - mu * mu;
    float sc = gamma[j] * rsqrtf(var + 1e-5f);
    float sh = beta[j] - mu * sc;
    ssb[j] = ((unsigned)f2b(sc) << 16) | (unsigned)f2b(sh);
}

__device__ __forceinline__ short8 bnrelu8(uint4 hv, uint4 sa, uint4 sb) {
    const unsigned short* hu = (const unsigned short*)&hv;
    const unsigned* wa = (const unsigned*)&sa;
    const unsigned* wb = (const unsigned*)&sb;
    float f[8];
#pragma unroll
    for (int j = 0; j < 8; ++j) {
        unsigned w = j < 4 ? wa[j] : wb[j - 4];
        float sc = __uint_as_float(w & 0xffff0000u);
        float sh = __uint_as_float(w << 16);
        f[j] = fmaxf(b2f(hu[j]) * sc + sh, 0.f);
    }
    union { unsigned u[4]; short8 s; } o;
#pragma unroll
    for (int j = 0; j < 4; ++j) o.u[j] = cvt_pk_bf16(f[2 * j], f[2 * j + 1]);
    return o.s;
}

// ---------------------------------------------------------------------------
// GEMM2 (R17): chunked-LDS A staging, BARRIER-FREE inner loop.
// q[M,N] += relu(bn(h))[M,K] * W2T[N,K]^T.
// Block: 64 rows x 256 cols (full N), 8 waves (512 thr), wave tile 32x64.
// A chunk h[64][512] is bnrelu'd ONCE into 64 KB LDS (XOR-8 slot swizzle:
// uniform 8-cy bank load on both write and ds_read_b128) behind a SINGLE
// __syncthreads. The 16 inner iters then have NO barriers: A-frags from LDS,
// B-frags (W2T, 2 MB L2-resident) loaded straight from global in MFMA
// fragment layout -> compiler pipelines loads freely across iterations.
// split-K x8; grid (1, M/64, 8).
__global__ __launch_bounds__(512, 4) void k_gemm2(
    const unsigned short* __restrict__ A, const unsigned short* __restrict__ Bt,
    float* __restrict__ Cout, const float* __restrict__ bias,
    const unsigned* __restrict__ ssb,
    int M, int N, int K) {
    constexpr int KC = 512;                       // k-chunk per block
    __shared__ __align__(16) short As[64 * KC];   // 64 KB

    const int t = threadIdx.x;
    const int lane = t & 63, wv = t >> 6;
    const int wr = wv >> 2, wc = wv & 3;          // 2 x 4 wave grid
    const int l15 = lane & 15, quad = lane >> 4;
    const int m0 = blockIdx.y * 64;
    const int kbeg = blockIdx.z * KC;

    // ---- stage: h[64][512] -> bnrelu -> LDS, slot' = slot ^ (row&7) ----
#pragma unroll
    for (int j = 0; j < 8; ++j) {
        int idx = j * 512 + t;
        int row = idx >> 6, c16 = idx & 63;       // 64 x 16B slots per row
        uint4 hv = *(const uint4*)(A + (size_t)(m0 + row) * K + kbeg + c16 * 8);
        uint4 sa = *(const uint4*)(ssb + kbeg + c16 * 8);
        uint4 sb = *(const uint4*)(ssb + kbeg + c16 * 8 + 4);
        int slot = c16 ^ (row & 7);
        *(short8*)(As + row * KC + slot * 8) = bnrelu8(hv, sa, sb);
    }
    __syncthreads();   // the ONLY barrier in the kernel

    f32x4 acc[2][4] = {};
    // B fragment base: row = wc*64 + ni*16 + l15 of W2T, k = kbeg + i*32 + quad*8
    const unsigned short* bp = Bt + (size_t)(wc * 64 + l15) * K + kbeg + quad * 8;

#pragma unroll 4
    for (int i = 0; i < 16; ++i) {
        short8 af[2], bfr[4];
#pragma unroll
        for (int ni = 0; ni < 4; ++ni)
            bfr[ni] = *(const short8*)(bp + (size_t)(ni * 16) * K + i * 32);
#pragma unroll
        for (int mi = 0; mi < 2; ++mi) {
            int row = wr * 32 + mi * 16 + l15;
            int slot = (i * 4 + quad) ^ (row & 7);
            af[mi] = *(const short8*)(As + row * KC + slot * 8);
        }
#pragma unroll
        for (int mi = 0; mi < 2; ++mi)
#pragma unroll
            for (int ni = 0; ni < 4; ++ni)
                acc[mi][ni] = __builtin_amdgcn_mfma_f32_16x16x32_bf16(
                    af[mi], bfr[ni], acc[mi][ni], 0, 0, 0);
    }

#pragma unroll
    for (int mi = 0; mi < 2; ++mi)
#pragma unroll
        for (int ni = 0; ni < 4; ++ni)
#pragma unroll
            for (int r = 0; r < 4; ++r) {
                int row = m0 + wr * 32 + mi * 16 + quad * 4 + r;
                int col = wc * 64 + ni * 16 + l15;
                float v = acc[mi][ni][r];
                if (blockIdx.z == 0) v += bias[col];
                atomicAdd(&Cout[(size_t)row * N + col], v);
            }
}

// ---------------------------------------------------------------------------
// Fused norm + transpose + cast (R14-proven): per 32-row slab of X [8192,256]
// f32: load to LDS, row inv-norms, write XT [256,8192] bf16 normalized.
// grid (B/32, 4), block 256.
__global__ __launch_bounds__(256) void k_ntc(
    const float* __restrict__ x0, const float* __restrict__ x1,
    const float* __restrict__ x2, const float* __restrict__ x3,
    unsigned short* __restrict__ o0, unsigned short* __restrict__ o1,
    unsigned short* __restrict__ o2, unsigned short* __restrict__ o3) {
    const int z = blockIdx.y;
    const float* x = z == 0 ? x0 : z == 1 ? x1 : z == 2 ? x2 : x3;
    unsigned short* out = z == 0 ? o0 : z == 1 ? o1 : z == 2 ? o2 : o3;

    __shared__ float tile[32][264];
    __shared__ float red[32][8];
    __shared__ float invs[32];
    const int t = threadIdx.x;
    const int r0 = blockIdx.x * 32;

#pragma unroll
    for (int i = 0; i < 8; ++i) {
        int u = i * 256 + t;
        int row = u >> 6, cp = (u & 63) * 4;
        float4 v = *(const float4*)(x + (size_t)(r0 + row) * E_DIM + cp);
        *(float4*)&tile[row][cp] = v;
    }
    __syncthreads();
    {
        int row = t >> 3, cg = (t & 7) * 32;
        float s = 0.f;
#pragma unroll
        for (int j = 0; j < 32; ++j) { float v = tile[row][cg + j]; s += v * v; }
        red[row][t & 7] = s;
    }
    __syncthreads();
    if (t < 32) {
        float s = 0.f;
#pragma unroll
        for (int j = 0; j < 8; ++j) s += red[t][j];
        invs[t] = 1.f / fmaxf(sqrtf(s), 1e-12f);
    }
    __syncthreads();
    {
        int row = t & 31, cb = (t >> 5) * 32;
        float inv = invs[row];
#pragma unroll
        for (int j = 0; j < 32; ++j) {
            int c = cb + j;
            out[(size_t)c * B_ROWS + r0 + row] = f2b(tile[row][c] * inv);
        }
    }
}

// ---------------------------------------------------------------------------
// Gram via MFMA: Mout[a,b] += sum_k AT[a,k]*BT[b,k], AT/BT bf16 [256,8192].
// BM=BN=64, BK=32, swizzled staging, split-K x16; grid (4,4,32).
#define GKS 16
__global__ __launch_bounds__(256) void k_gram(
    const unsigned short* __restrict__ p1T, const unsigned short* __restrict__ q2T,
    const unsigned short* __restrict__ p2T, const unsigned short* __restrict__ q1T,
    float* __restrict__ Ma, float* __restrict__ Mb) {
    constexpr int BK = 32;
    const int mec = blockIdx.z >> 4, kz = blockIdx.z & 15;
    const unsigned short* A = mec ? p2T : p1T;
    const unsigned short* Bt = mec ? q1T : q2T;
    float* Mout = mec ? Mb : Ma;

    __shared__ __align__(16) short As[64 * BK];
    __shared__ __align__(16) short Bs[64 * BK];

    const int t = threadIdx.x;
    const int lane = t & 63, wv = t >> 6;
    const int wr = wv >> 1, wc = wv & 1;
    const int l15 = lane & 15, quad = lane >> 4;
    const int m0 = blockIdx.y * 64, n0 = blockIdx.x * 64;
    const int kbeg = kz * (B_ROWS / GKS);

    f32x4 acc[2][2] = {};

    for (int k0 = kbeg; k0 < kbeg + B_ROWS / GKS; k0 += BK) {
        {
            int row = t >> 2, kc = swz(row, t & 3);
            const short* gpa = (const short*)A + (size_t)(m0 + row) * B_ROWS + k0 + kc * 8;
            short* lpa = As + (size_t)(wv << 6) * 8;
            __builtin_amdgcn_global_load_lds((gas1_t)gpa, (las3_t)lpa, 16, 0, 0);
            const short* gpb = (const short*)Bt + (size_t)(n0 + row) * B_ROWS + k0 + kc * 8;
            short* lpb = Bs + (size_t)(wv << 6) * 8;
            __builtin_amdgcn_global_load_lds((gas1_t)gpb, (las3_t)lpb, 16, 0, 0);
        }
        __syncthreads();

        short8 af[2], bfr[2];
#pragma unroll
        for (int mi = 0; mi < 2; ++mi) {
            int row = wr * 32 + mi * 16 + l15;
            af[mi] = *(const short8*)(As + row * BK + (swz(row, quad) << 3));
        }
#pragma unroll
        for (int ni = 0; ni < 2; ++ni) {
            int row = wc * 32 + ni * 16 + l15;
            bfr[ni] = *(const short8*)(Bs + row * BK + (swz(row, quad) << 3));
        }
#pragma unroll
        for (int mi = 0; mi < 2; ++mi)
#pragma unroll
            for (int ni = 0; ni < 2; ++ni)
                acc[mi][ni] = __builtin_amdgcn_mfma_f32_16x16x32_bf16(
                    af[mi], bfr[ni], acc[mi][ni], 0, 0, 0);
        __syncthreads();
    }

#pragma unroll
    for (int mi = 0; mi < 2; ++mi)
#pragma unroll
        for (int ni = 0; ni < 2; ++ni)
#pragma unroll
            for (int r = 0; r < 4; ++r) {
                int row = m0 + wr * 32 + mi * 16 + quad * 4 + r;
                int col = n0 + wc * 32 + ni * 16 + l15;
                atomicAdd(&Mout[(size_t)row * E_DIM + col], acc[mi][ni][r]);
            }
}

// M2 = M*M (256x256). grid (16,16,2) block 256.
__global__ void k_m2(const float* __restrict__ Ma, const float* __restrict__ Mb,
                     float* __restrict__ M2a, float* __restrict__ M2b) {
    const float* M = blockIdx.z ? Mb : Ma;
    float* M2 = blockIdx.z ? M2b : M2a;
    int b = blockIdx.x * 16 + (threadIdx.x & 15);
    int a = blockIdx.y * 16 + (threadIdx.x >> 4);
    float s = 0.f;
    for (int k = 0; k < E_DIM; ++k) s += M[a * E_DIM + k] * M[k * E_DIM + b];
    M2[a * E_DIM + b] = s;
}

// ---------------------------------------------------------------------------
// Traces, tiled multi-block: grid (8,8,2), block 256.
__global__ __launch_bounds__(256) void k_traces2(
    const float* __restrict__ Ma, const float* __restrict__ M2a,
    const float* __restrict__ Mb, const float* __restrict__ M2b,
    const float* __restrict__ lam, float* __restrict__ out) {
    const float* M  = blockIdx.z ? Mb  : Ma;
    const float* M2 = blockIdx.z ? M2b : M2a;
    const int i0 = blockIdx.y * 32, j0 = blockIdx.x * 32;
    const int t = threadIdx.x, col = t & 31, row = t >> 5;  // row 0..7

    __shared__ float A[32][33], Bt[32][33], A2[32][33], B2[32][33];
#pragma unroll
    for (int r = 0; r < 4; ++r) {
        int rr = r * 8 + row;
        A [rr][col] = M [(i0 + rr) * E_DIM + j0 + col];
        Bt[rr][col] = M [(j0 + rr) * E_DIM + i0 + col];
        A2[rr][col] = M2[(i0 + rr) * E_DIM + j0 + col];
        B2[rr][col] = M2[(j0 + rr) * E_DIM + i0 + col];
    }
    __syncthreads();

    float lamv = lam[0];
    float il = 1.f / lamv;
    float F = -0.5f * lamv * (1.f / B_ROWS);  // -0.5*lam/B
    float c1 = F * il;
    float c2 = -F * 0.5f * il * il;
    float c3 = F * (1.f / 3.f) * il * il * il;
    float c4 = -F * 0.25f * il * il * il * il;

    float s = 0.f;
#pragma unroll
    for (int r = 0; r < 4; ++r) {
        int rr = r * 8 + row;
        float mij = A[rr][col], mji = Bt[col][rr];
        float m2ij = A2[rr][col], m2ji = B2[col][rr];
        s += c2 * mij * mji + c3 * m2ij * mji + c4 * m2ij * m2ji;
        if (i0 + rr == j0 + col) s += c1 * mij;
    }
#pragma unroll
    for (int o = 32; o; o >>= 1) s += __shfl_down(s, o);
    __shared__ float red[4];
    if ((t & 63) == 0) red[t >> 6] = s;
    __syncthreads();
    if (t == 0) atomicAdd(out, red[0] + red[1] + red[2] + red[3]);
}

// ---------------------------------------------------------------------------
extern "C" void kernel_launch(void* const* d_in, const int* in_sizes, int n_in,
                              void* d_out, int out_size, void* d_ws, size_t ws_size,
                              hipStream_t stream) {
    const float* z1 = (const float*)d_in[0];
    const float* z2 = (const float*)d_in[1];
    const float* p1 = (const float*)d_in[2];
    const float* p2 = (const float*)d_in[3];
    const float* W1 = (const float*)d_in[4];
    const float* gamma = (const float*)d_in[5];
    const float* beta = (const float*)d_in[6];
    const float* W2 = (const float*)d_in[7];
    const float* b2 = (const float*)d_in[8];
    const float* lam = (const float*)d_in[9];
    float* out = (float*)d_out;
    char* ws = (char*)d_ws;

    // workspace layout (~89 MB)
    size_t off = 0;
    auto alloc = [&](size_t bytes) { size_t o = off; off += (bytes + 255) & ~(size_t)255; return o; };
    unsigned short* W1T = (unsigned short*)(ws + alloc((size_t)E_DIM * H_DIM * 2));  // [H,E] bf16
    unsigned short* W2T = (unsigned short*)(ws + alloc((size_t)H_DIM * E_DIM * 2));  // [E,H] bf16
    unsigned short* zb  = (unsigned short*)(ws + alloc((size_t)B_ROWS * E_DIM * 2));
    unsigned short* h   = (unsigned short*)(ws + alloc((size_t)B_ROWS * H_DIM * 2));
    // q1,q2,Ma,Mb contiguous -> single memset
    float* q1 = (float*)(ws + alloc((size_t)B_ROWS * E_DIM * 4));
    float* q2 = (float*)(ws + alloc((size_t)B_ROWS * E_DIM * 4));
    float* Ma  = (float*)(ws + alloc((size_t)E_DIM * E_DIM * 4));
    float* Mb  = (float*)(ws + alloc((size_t)E_DIM * E_DIM * 4));
    float* M2a = (float*)(ws + alloc((size_t)E_DIM * E_DIM * 4));
    float* M2b = (float*)(ws + alloc((size_t)E_DIM * E_DIM * 4));
    // two colsum sets (one per view), contiguous -> single memset
    float* cs0 = (float*)(ws + alloc(H_DIM * 4));
    float* cs0q = (float*)(ws + alloc(H_DIM * 4));
    float* cs1 = (float*)(ws + alloc(H_DIM * 4));
    float* cs1q = (float*)(ws + alloc(H_DIM * 4));
    unsigned* ssb = (unsigned*)(ws + alloc(H_DIM * 4));

    // transposed normalized bf16 views alias into h (free after last GEMM2)
    const size_t TSZ = (size_t)E_DIM * B_ROWS;  // 2M elements each
    unsigned short* p1T = h;
    unsigned short* q2T = h + TSZ;
    unsigned short* p2T = h + 2 * TSZ;
    unsigned short* q1T = h + 3 * TSZ;

    // zero accumulation targets (3 memsets total)
    hipMemsetAsync(out, 0, sizeof(float), stream);
    hipMemsetAsync(q1, 0, ((size_t)2 * B_ROWS * E_DIM + 2 * E_DIM * E_DIM) * 4, stream);
    hipMemsetAsync(cs0, 0, (size_t)4 * H_DIM * 4, stream);

    // weight transposes (k-contiguous operands for MFMA)
    k_transpose_cast<<<dim3(H_DIM / 32, E_DIM / 32), 256, 0, stream>>>(W1, W1T, E_DIM, H_DIM);
    k_transpose_cast<<<dim3(E_DIM / 32, H_DIM / 32), 256, 0, stream>>>(W2, W2T, H_DIM, E_DIM);

    const float* zs[2] = {z1, z2};
    float* qs[2] = {q1, q2};
    float* css[2] = {cs0, cs1};
    float* cssq[2] = {cs0q, cs1q};
    for (int v = 0; v < 2; ++v) {
        k_cast_bf16<<<dim3(B_ROWS * E_DIM / 4 / 256), 256, 0, stream>>>(zs[v], zb, B_ROWS * E_DIM / 4);
        // h = z @ W1, with fused column stats
        k_gemm1<<<dim3(H_DIM / 128, B_ROWS / 128), 256, 0, stream>>>(
            zb, W1T, h, css[v], cssq[v], B_ROWS, H_DIM, E_DIM);
        k_bnprep<<<dim3(H_DIM / 256), 256, 0, stream>>>(css[v], cssq[v], gamma, beta, ssb);
        // q = relu(bn(h)) @ W2 + b2 — one-barrier chunked-LDS design, split-K x8
        k_gemm2<<<dim3(1, B_ROWS / 64, 8), 512, 0, stream>>>(
            h, W2T, qs[v], b2, ssb, B_ROWS, E_DIM, H_DIM);
    }

    // fused row-norm + transpose + cast of p1,q2,p2,q1 (into h's space)
    k_ntc<<<dim3(B_ROWS / 32, 4), 256, 0, stream>>>(
        p1, q2, p2, q1, p1T, q2T, p2T, q1T);

    k_gram<<<dim3(4, 4, 2 * GKS), 256, 0, stream>>>(p1T, q2T, p2T, q1T, Ma, Mb);
    k_m2<<<dim3(16, 16, 2), 256, 0, stream>>>(Ma, Mb, M2a, M2b);
    k_traces2<<<dim3(8, 8, 2), 256, 0, stream>>>(Ma, M2a, Mb, M2b, lam, out);
}

// Round 3
// 374.957 us; speedup vs baseline: 1.0625x; 1.0625x over previous
//
#include <hip/hip_runtime.h>

// Problem constants (fixed by reference)
#define B_ROWS 8192
#define E_DIM  256
#define H_DIM  4096

typedef __attribute__((ext_vector_type(8))) short short8;
typedef __attribute__((ext_vector_type(4))) float f32x4;

typedef __attribute__((address_space(1))) const void* gas1_t;
typedef __attribute__((address_space(3))) void*       las3_t;

__device__ __forceinline__ float b2f(unsigned short s) {
    return __uint_as_float(((unsigned)s) << 16);
}
__device__ __forceinline__ unsigned short f2b(float f) {
    unsigned u = __float_as_uint(f);
    u += 0x7fffu + ((u >> 16) & 1u);   // RNE
    return (unsigned short)(u >> 16);
}

// HW packed f32->bf16 convert (1 instr for 2 elems vs 4 VALU ops each).
// GEMM2 A-path only; absmax bit-identical (7.63e-6) across R16/R17.
__device__ __forceinline__ unsigned cvt_pk_bf16(float lo, float hi) {
    unsigned r;
    asm("v_cvt_pk_bf16_f32 %0, %1, %2" : "=v"(r) : "v"(lo), "v"(hi));
    return r;
}

// LDS swizzle for BK=32 (64B rows, 4x16B slots): slot' = slot ^ ((row>>1)&3)
// -> ds_read_b128 fragment reads are 2-way (free, m136) instead of 8-way.
__device__ __forceinline__ int swz(int row, int slot) {
    return slot ^ ((row >> 1) & 3);
}

// ---------------------------------------------------------------------------
// Transpose + cast f32 [R,C] -> bf16 [C,R]
__global__ void k_transpose_cast(const float* __restrict__ in,
                                 unsigned short* __restrict__ out,
                                 int R, int C) {
    __shared__ float tile[32][33];
    const int c0 = blockIdx.x * 32, r0 = blockIdx.y * 32;
    const int tx = threadIdx.x & 31, ty = threadIdx.x >> 5;  // ty 0..7
#pragma unroll
    for (int j = 0; j < 4; ++j)
        tile[ty * 4 + j][tx] = in[(size_t)(r0 + ty * 4 + j) * C + c0 + tx];
    __syncthreads();
#pragma unroll
    for (int j = 0; j < 4; ++j)
        out[(size_t)(c0 + ty * 4 + j) * R + r0 + tx] = f2b(tile[tx][ty * 4 + j]);
}

// ---------------------------------------------------------------------------
// Cast f32 -> bf16, 4 elems/thread.
__global__ void k_cast_bf16(const float* __restrict__ in,
                            unsigned short* __restrict__ out, int n4) {
    int i = blockIdx.x * blockDim.x + threadIdx.x;
    if (i < n4) {
        float4 v = ((const float4*)in)[i];
        ushort4 o;
        o.x = f2b(v.x); o.y = f2b(v.y); o.z = f2b(v.z); o.w = f2b(v.w);
        ((ushort4*)out)[i] = o;
    }
}

// ---------------------------------------------------------------------------
// GEMM1 (R10 proven): h[M,N] = A[M,K] * Bt[N,K]^T, bf16 out + fused col stats.
// BM=BN=128, BK=32, swizzled global_load_lds staging. grid (N/128, M/128).
__global__ __launch_bounds__(256) void k_gemm1(
    const unsigned short* __restrict__ A, const unsigned short* __restrict__ Bt,
    unsigned short* __restrict__ Cout,
    float* __restrict__ cs, float* __restrict__ cs2,
    int M, int N, int K) {
    constexpr int BK = 32, BM = 128, BN = 128;
    constexpr int MI = 4, NI = 4;
    __shared__ __align__(16) short As[BM * BK];
    __shared__ __align__(16) short Bs[BN * BK];

    const int t = threadIdx.x;
    const int lane = t & 63, wv = t >> 6;
    const int wr = wv >> 1, wc = wv & 1;
    const int l15 = lane & 15, quad = lane >> 4;
    const int m0 = blockIdx.y * BM, n0 = blockIdx.x * BN;

    f32x4 acc[MI][NI] = {};

    for (int k0 = 0; k0 < K; k0 += BK) {
#pragma unroll
        for (int q = 0; q < 2; ++q) {
            int u = q * 256 + t;
            int row = u >> 2, kc = swz(row, u & 3);
            const short* gp = (const short*)A + (size_t)(m0 + row) * K + k0 + kc * 8;
            short* lp = As + (size_t)(q * 256 + (wv << 6)) * 8;  // wave-uniform base
            __builtin_amdgcn_global_load_lds((gas1_t)gp, (las3_t)lp, 16, 0, 0);
        }
#pragma unroll
        for (int q = 0; q < 2; ++q) {
            int u = q * 256 + t;
            int row = u >> 2, kc = swz(row, u & 3);
            const short* gp = (const short*)Bt + (size_t)(n0 + row) * K + k0 + kc * 8;
            short* lp = Bs + (size_t)(q * 256 + (wv << 6)) * 8;
            __builtin_amdgcn_global_load_lds((gas1_t)gp, (las3_t)lp, 16, 0, 0);
        }
        __syncthreads();

        short8 af[MI], bfr[NI];
#pragma unroll
        for (int mi = 0; mi < MI; ++mi) {
            int row = wr * 64 + mi * 16 + l15;
            af[mi] = *(const short8*)(As + row * BK + (swz(row, quad) << 3));
        }
#pragma unroll
        for (int ni = 0; ni < NI; ++ni) {
            int row = wc * 64 + ni * 16 + l15;
            bfr[ni] = *(const short8*)(Bs + row * BK + (swz(row, quad) << 3));
        }
#pragma unroll
        for (int mi = 0; mi < MI; ++mi)
#pragma unroll
            for (int ni = 0; ni < NI; ++ni)
                acc[mi][ni] = __builtin_amdgcn_mfma_f32_16x16x32_bf16(
                    af[mi], bfr[ni], acc[mi][ni], 0, 0, 0);
        __syncthreads();
    }

    // epilogue: C/D layout col=lane&15, row=quad*4+reg (measured m89)
#pragma unroll
    for (int ni = 0; ni < NI; ++ni) {
        float s = 0.f, s2 = 0.f;
#pragma unroll
        for (int mi = 0; mi < MI; ++mi)
#pragma unroll
            for (int r = 0; r < 4; ++r) {
                int row = m0 + wr * 64 + mi * 16 + quad * 4 + r;
                int col = n0 + wc * 64 + ni * 16 + l15;
                float v = acc[mi][ni][r];
                Cout[(size_t)row * N + col] = f2b(v);
                s += v; s2 += v * v;
            }
        s  += __shfl_xor(s, 16);  s  += __shfl_xor(s, 32);
        s2 += __shfl_xor(s2, 16); s2 += __shfl_xor(s2, 32);
        if (quad == 0) {
            int col = n0 + wc * 64 + ni * 16 + l15;
            atomicAdd(&cs[col], s);
            atomicAdd(&cs2[col], s2);
        }
    }
}

// BN scale/shift packed as bf16 pair: ssb[k] = f2b(scale)<<16 | f2b(shift)
// (bf16 params verified numerically R6/R9/R10/R14: absmax 7.6e-6 vs 2e-5 thr)
__global__ void k_bnprep(const float* __restrict__ sum, const float* __restrict__ sumsq,
                         const float* __restrict__ gamma, const float* __restrict__ beta,
                         unsigned* __restrict__ ssb) {
    int j = blockIdx.x * 256 + threadIdx.x;
    float mu = sum[j] * (1.f / B_ROWS);
    float var = sumsq[j] * (1.f / B_ROWS) - mu * mu;
    float sc = gamma[j] * rsqrtf(var + 1e-5f);
    float sh = beta[j] - mu * sc;
    ssb[j] = ((unsigned)f2b(sc) << 16) | (unsigned)f2b(sh);
}

__device__ __forceinline__ short8 bnrelu8(uint4 hv, uint4 sa, uint4 sb) {
    const unsigned short* hu = (const unsigned short*)&hv;
    const unsigned* wa = (const unsigned*)&sa;
    const unsigned* wb = (const unsigned*)&sb;
    float f[8];
#pragma unroll
    for (int j = 0; j < 8; ++j) {
        unsigned w = j < 4 ? wa[j] : wb[j - 4];
        float sc = __uint_as_float(w & 0xffff0000u);
        float sh = __uint_as_float(w << 16);
        f[j] = fmaxf(b2f(hu[j]) * sc + sh, 0.f);
    }
    union { unsigned u[4]; short8 s; } o;
#pragma unroll
    for (int j = 0; j < 4; ++j) o.u[j] = cvt_pk_bf16(f[2 * j], f[2 * j + 1]);
    return o.s;
}

// ---------------------------------------------------------------------------
// GEMM2 (R10's winning structure, reverted): register-staged DOUBLE-BUFFERED,
// lgkm-only barriers. q[M,N] += relu(bn(h))[M,K] * W2T[N,K]^T.
// BM=64, BN=128, BK=32. R18 deltas vs R10: split-K x8 (grid 2048 blocks ->
// 6 blocks/CU LDS-limited = 24 waves/CU cap, vs R10's grid-limited 4 blocks
// = 16 waves; R10's occupancy was grid-bound, not resource-bound) and
// cvt_pk bnrelu (VALU trim, absmax-neutral R16/R17).
__global__ __launch_bounds__(256) void k_gemm2d(
    const unsigned short* __restrict__ A, const unsigned short* __restrict__ Bt,
    float* __restrict__ Cout, const float* __restrict__ bias,
    const unsigned* __restrict__ ssb,
    int M, int N, int K) {
    constexpr int BK = 32, BM = 64, BN = 128;
    constexpr int MI = 2, NI = 4;
    __shared__ __align__(16) short As[2][BM * BK];   // 2 x 4 KB
    __shared__ __align__(16) short Bs[2][BN * BK];   // 2 x 8 KB

    const int t = threadIdx.x;
    const int lane = t & 63, wv = t >> 6;
    const int wr = wv >> 1, wc = wv & 1;
    const int l15 = lane & 15, quad = lane >> 4;
    const int m0 = blockIdx.y * BM, n0 = blockIdx.x * BN;

    const int Kc = K / gridDim.z;
    const int kbeg = blockIdx.z * Kc;
    const int ITERS = Kc / BK;

    const int arow = t >> 2, akc = t & 3;
    const unsigned short* hp = A + (size_t)(m0 + arow) * K + akc * 8;
    const unsigned* ssp = ssb + akc * 8;
    const int awoff = arow * BK + (swz(arow, akc) << 3);

    const unsigned short* bp0 = Bt + (size_t)(n0 + arow) * K + akc * 8;
    const unsigned short* bp1 = Bt + (size_t)(n0 + 64 + arow) * K + akc * 8;
    const int bwoff0 = arow * BK + (swz(arow, akc) << 3);
    const int bwoff1 = (64 + arow) * BK + (swz(64 + arow, akc) << 3);

    f32x4 acc[MI][NI] = {};

    uint4 hreg = *(const uint4*)(hp + kbeg);
    uint4 sa = *(const uint4*)(ssp + kbeg);
    uint4 sb = *(const uint4*)(ssp + kbeg + 4);
    uint4 b0 = *(const uint4*)(bp0 + kbeg);
    uint4 b1 = *(const uint4*)(bp1 + kbeg);

    for (int i = 0; i < ITERS; ++i) {
        const int k0 = kbeg + i * BK;
        short* Ab = As[i & 1];
        short* Bb = Bs[i & 1];

        *(short8*)(Ab + awoff) = bnrelu8(hreg, sa, sb);
        *(uint4*)(Bb + bwoff0) = b0;
        *(uint4*)(Bb + bwoff1) = b1;
        __syncthreads();   // lgkm-only drain

        const int kn = (i + 1 < ITERS) ? k0 + BK : kbeg;
        hreg = *(const uint4*)(hp + kn);
        sa = *(const uint4*)(ssp + kn);
        sb = *(const uint4*)(ssp + kn + 4);
        b0 = *(const uint4*)(bp0 + kn);
        b1 = *(const uint4*)(bp1 + kn);

        short8 af[MI], bfr[NI];
#pragma unroll
        for (int mi = 0; mi < MI; ++mi) {
            int row = wr * 32 + mi * 16 + l15;
            af[mi] = *(const short8*)(Ab + row * BK + (swz(row, quad) << 3));
        }
#pragma unroll
        for (int ni = 0; ni < NI; ++ni) {
            int row = wc * 64 + ni * 16 + l15;
            bfr[ni] = *(const short8*)(Bb + row * BK + (swz(row, quad) << 3));
        }
#pragma unroll
        for (int mi = 0; mi < MI; ++mi)
#pragma unroll
            for (int ni = 0; ni < NI; ++ni)
                acc[mi][ni] = __builtin_amdgcn_mfma_f32_16x16x32_bf16(
                    af[mi], bfr[ni], acc[mi][ni], 0, 0, 0);
    }

#pragma unroll
    for (int mi = 0; mi < MI; ++mi)
#pragma unroll
        for (int ni = 0; ni < NI; ++ni)
#pragma unroll
            for (int r = 0; r < 4; ++r) {
                int row = m0 + wr * 32 + mi * 16 + quad * 4 + r;
                int col = n0 + wc * 64 + ni * 16 + l15;
                float v = acc[mi][ni][r];
                if (blockIdx.z == 0) v += bias[col];
                atomicAdd(&Cout[(size_t)row * N + col], v);
            }
}

// ---------------------------------------------------------------------------
// Fused norm + transpose + cast (R14-proven): per 32-row slab of X [8192,256]
// f32: load to LDS, row inv-norms, write XT [256,8192] bf16 normalized.
// grid (B/32, 4), block 256.
__global__ __launch_bounds__(256) void k_ntc(
    const float* __restrict__ x0, const float* __restrict__ x1,
    const float* __restrict__ x2, const float* __restrict__ x3,
    unsigned short* __restrict__ o0, unsigned short* __restrict__ o1,
    unsigned short* __restrict__ o2, unsigned short* __restrict__ o3) {
    const int z = blockIdx.y;
    const float* x = z == 0 ? x0 : z == 1 ? x1 : z == 2 ? x2 : x3;
    unsigned short* out = z == 0 ? o0 : z == 1 ? o1 : z == 2 ? o2 : o3;

    __shared__ float tile[32][264];
    __shared__ float red[32][8];
    __shared__ float invs[32];
    const int t = threadIdx.x;
    const int r0 = blockIdx.x * 32;

#pragma unroll
    for (int i = 0; i < 8; ++i) {
        int u = i * 256 + t;
        int row = u >> 6, cp = (u & 63) * 4;
        float4 v = *(const float4*)(x + (size_t)(r0 + row) * E_DIM + cp);
        *(float4*)&tile[row][cp] = v;
    }
    __syncthreads();
    {
        int row = t >> 3, cg = (t & 7) * 32;
        float s = 0.f;
#pragma unroll
        for (int j = 0; j < 32; ++j) { float v = tile[row][cg + j]; s += v * v; }
        red[row][t & 7] = s;
    }
    __syncthreads();
    if (t < 32) {
        float s = 0.f;
#pragma unroll
        for (int j = 0; j < 8; ++j) s += red[t][j];
        invs[t] = 1.f / fmaxf(sqrtf(s), 1e-12f);
    }
    __syncthreads();
    {
        int row = t & 31, cb = (t >> 5) * 32;
        float inv = invs[row];
#pragma unroll
        for (int j = 0; j < 32; ++j) {
            int c = cb + j;
            out[(size_t)c * B_ROWS + r0 + row] = f2b(tile[row][c] * inv);
        }
    }
}

// ---------------------------------------------------------------------------
// Gram via MFMA: Mout[a,b] += sum_k AT[a,k]*BT[b,k], AT/BT bf16 [256,8192].
// BM=BN=64, BK=32, swizzled staging, split-K x16; grid (4,4,32).
#define GKS 16
__global__ __launch_bounds__(256) void k_gram(
    const unsigned short* __restrict__ p1T, const unsigned short* __restrict__ q2T,
    const unsigned short* __restrict__ p2T, const unsigned short* __restrict__ q1T,
    float* __restrict__ Ma, float* __restrict__ Mb) {
    constexpr int BK = 32;
    const int mec = blockIdx.z >> 4, kz = blockIdx.z & 15;
    const unsigned short* A = mec ? p2T : p1T;
    const unsigned short* Bt = mec ? q1T : q2T;
    float* Mout = mec ? Mb : Ma;

    __shared__ __align__(16) short As[64 * BK];
    __shared__ __align__(16) short Bs[64 * BK];

    const int t = threadIdx.x;
    const int lane = t & 63, wv = t >> 6;
    const int wr = wv >> 1, wc = wv & 1;
    const int l15 = lane & 15, quad = lane >> 4;
    const int m0 = blockIdx.y * 64, n0 = blockIdx.x * 64;
    const int kbeg = kz * (B_ROWS / GKS);

    f32x4 acc[2][2] = {};

    for (int k0 = kbeg; k0 < kbeg + B_ROWS / GKS; k0 += BK) {
        {
            int row = t >> 2, kc = swz(row, t & 3);
            const short* gpa = (const short*)A + (size_t)(m0 + row) * B_ROWS + k0 + kc * 8;
            short* lpa = As + (size_t)(wv << 6) * 8;
            __builtin_amdgcn_global_load_lds((gas1_t)gpa, (las3_t)lpa, 16, 0, 0);
            const short* gpb = (const short*)Bt + (size_t)(n0 + row) * B_ROWS + k0 + kc * 8;
            short* lpb = Bs + (size_t)(wv << 6) * 8;
            __builtin_amdgcn_global_load_lds((gas1_t)gpb, (las3_t)lpb, 16, 0, 0);
        }
        __syncthreads();

        short8 af[2], bfr[2];
#pragma unroll
        for (int mi = 0; mi < 2; ++mi) {
            int row = wr * 32 + mi * 16 + l15;
            af[mi] = *(const short8*)(As + row * BK + (swz(row, quad) << 3));
        }
#pragma unroll
        for (int ni = 0; ni < 2; ++ni) {
            int row = wc * 32 + ni * 16 + l15;
            bfr[ni] = *(const short8*)(Bs + row * BK + (swz(row, quad) << 3));
        }
#pragma unroll
        for (int mi = 0; mi < 2; ++mi)
#pragma unroll
            for (int ni = 0; ni < 2; ++ni)
                acc[mi][ni] = __builtin_amdgcn_mfma_f32_16x16x32_bf16(
                    af[mi], bfr[ni], acc[mi][ni], 0, 0, 0);
        __syncthreads();
    }

#pragma unroll
    for (int mi = 0; mi < 2; ++mi)
#pragma unroll
        for (int ni = 0; ni < 2; ++ni)
#pragma unroll
            for (int r = 0; r < 4; ++r) {
                int row = m0 + wr * 32 + mi * 16 + quad * 4 + r;
                int col = n0 + wc * 32 + ni * 16 + l15;
                atomicAdd(&Mout[(size_t)row * E_DIM + col], acc[mi][ni][r]);
            }
}

// M2 = M*M (256x256). grid (16,16,2) block 256.
__global__ void k_m2(const float* __restrict__ Ma, const float* __restrict__ Mb,
                     float* __restrict__ M2a, float* __restrict__ M2b) {
    const float* M = blockIdx.z ? Mb : Ma;
    float* M2 = blockIdx.z ? M2b : M2a;
    int b = blockIdx.x * 16 + (threadIdx.x & 15);
    int a = blockIdx.y * 16 + (threadIdx.x >> 4);
    float s = 0.f;
    for (int k = 0; k < E_DIM; ++k) s += M[a * E_DIM + k] * M[k * E_DIM + b];
    M2[a * E_DIM + b] = s;
}

// ---------------------------------------------------------------------------
// Traces, tiled multi-block: grid (8,8,2), block 256.
__global__ __launch_bounds__(256) void k_traces2(
    const float* __restrict__ Ma, const float* __restrict__ M2a,
    const float* __restrict__ Mb, const float* __restrict__ M2b,
    const float* __restrict__ lam, float* __restrict__ out) {
    const float* M  = blockIdx.z ? Mb  : Ma;
    const float* M2 = blockIdx.z ? M2b : M2a;
    const int i0 = blockIdx.y * 32, j0 = blockIdx.x * 32;
    const int t = threadIdx.x, col = t & 31, row = t >> 5;  // row 0..7

    __shared__ float A[32][33], Bt[32][33], A2[32][33], B2[32][33];
#pragma unroll
    for (int r = 0; r < 4; ++r) {
        int rr = r * 8 + row;
        A [rr][col] = M [(i0 + rr) * E_DIM + j0 + col];
        Bt[rr][col] = M [(j0 + rr) * E_DIM + i0 + col];
        A2[rr][col] = M2[(i0 + rr) * E_DIM + j0 + col];
        B2[rr][col] = M2[(j0 + rr) * E_DIM + i0 + col];
    }
    __syncthreads();

    float lamv = lam[0];
    float il = 1.f / lamv;
    float F = -0.5f * lamv * (1.f / B_ROWS);  // -0.5*lam/B
    float c1 = F * il;
    float c2 = -F * 0.5f * il * il;
    float c3 = F * (1.f / 3.f) * il * il * il;
    float c4 = -F * 0.25f * il * il * il * il;

    float s = 0.f;
#pragma unroll
    for (int r = 0; r < 4; ++r) {
        int rr = r * 8 + row;
        float mij = A[rr][col], mji = Bt[col][rr];
        float m2ij = A2[rr][col], m2ji = B2[col][rr];
        s += c2 * mij * mji + c3 * m2ij * mji + c4 * m2ij * m2ji;
        if (i0 + rr == j0 + col) s += c1 * mij;
    }
#pragma unroll
    for (int o = 32; o; o >>= 1) s += __shfl_down(s, o);
    __shared__ float red[4];
    if ((t & 63) == 0) red[t >> 6] = s;
    __syncthreads();
    if (t == 0) atomicAdd(out, red[0] + red[1] + red[2] + red[3]);
}

// ---------------------------------------------------------------------------
extern "C" void kernel_launch(void* const* d_in, const int* in_sizes, int n_in,
                              void* d_out, int out_size, void* d_ws, size_t ws_size,
                              hipStream_t stream) {
    const float* z1 = (const float*)d_in[0];
    const float* z2 = (const float*)d_in[1];
    const float* p1 = (const float*)d_in[2];
    const float* p2 = (const float*)d_in[3];
    const float* W1 = (const float*)d_in[4];
    const float* gamma = (const float*)d_in[5];
    const float* beta = (const float*)d_in[6];
    const float* W2 = (const float*)d_in[7];
    const float* b2 = (const float*)d_in[8];
    const float* lam = (const float*)d_in[9];
    float* out = (float*)d_out;
    char* ws = (char*)d_ws;

    // workspace layout (~89 MB)
    size_t off = 0;
    auto alloc = [&](size_t bytes) { size_t o = off; off += (bytes + 255) & ~(size_t)255; return o; };
    unsigned short* W1T = (unsigned short*)(ws + alloc((size_t)E_DIM * H_DIM * 2));  // [H,E] bf16
    unsigned short* W2T = (unsigned short*)(ws + alloc((size_t)H_DIM * E_DIM * 2));  // [E,H] bf16
    unsigned short* zb  = (unsigned short*)(ws + alloc((size_t)B_ROWS * E_DIM * 2));
    unsigned short* h   = (unsigned short*)(ws + alloc((size_t)B_ROWS * H_DIM * 2));
    // q1,q2,Ma,Mb contiguous -> single memset
    float* q1 = (float*)(ws + alloc((size_t)B_ROWS * E_DIM * 4));
    float* q2 = (float*)(ws + alloc((size_t)B_ROWS * E_DIM * 4));
    float* Ma  = (float*)(ws + alloc((size_t)E_DIM * E_DIM * 4));
    float* Mb  = (float*)(ws + alloc((size_t)E_DIM * E_DIM * 4));
    float* M2a = (float*)(ws + alloc((size_t)E_DIM * E_DIM * 4));
    float* M2b = (float*)(ws + alloc((size_t)E_DIM * E_DIM * 4));
    // two colsum sets (one per view), contiguous -> single memset
    float* cs0 = (float*)(ws + alloc(H_DIM * 4));
    float* cs0q = (float*)(ws + alloc(H_DIM * 4));
    float* cs1 = (float*)(ws + alloc(H_DIM * 4));
    float* cs1q = (float*)(ws + alloc(H_DIM * 4));
    unsigned* ssb = (unsigned*)(ws + alloc(H_DIM * 4));

    // transposed normalized bf16 views alias into h (free after last GEMM2)
    const size_t TSZ = (size_t)E_DIM * B_ROWS;  // 2M elements each
    unsigned short* p1T = h;
    unsigned short* q2T = h + TSZ;
    unsigned short* p2T = h + 2 * TSZ;
    unsigned short* q1T = h + 3 * TSZ;

    // zero accumulation targets (3 memsets total)
    hipMemsetAsync(out, 0, sizeof(float), stream);
    hipMemsetAsync(q1, 0, ((size_t)2 * B_ROWS * E_DIM + 2 * E_DIM * E_DIM) * 4, stream);
    hipMemsetAsync(cs0, 0, (size_t)4 * H_DIM * 4, stream);

    // weight transposes (k-contiguous operands for MFMA)
    k_transpose_cast<<<dim3(H_DIM / 32, E_DIM / 32), 256, 0, stream>>>(W1, W1T, E_DIM, H_DIM);
    k_transpose_cast<<<dim3(E_DIM / 32, H_DIM / 32), 256, 0, stream>>>(W2, W2T, H_DIM, E_DIM);

    const float* zs[2] = {z1, z2};
    float* qs[2] = {q1, q2};
    float* css[2] = {cs0, cs1};
    float* cssq[2] = {cs0q, cs1q};
    for (int v = 0; v < 2; ++v) {
        k_cast_bf16<<<dim3(B_ROWS * E_DIM / 4 / 256), 256, 0, stream>>>(zs[v], zb, B_ROWS * E_DIM / 4);
        // h = z @ W1, with fused column stats
        k_gemm1<<<dim3(H_DIM / 128, B_ROWS / 128), 256, 0, stream>>>(
            zb, W1T, h, css[v], cssq[v], B_ROWS, H_DIM, E_DIM);
        k_bnprep<<<dim3(H_DIM / 256), 256, 0, stream>>>(css[v], cssq[v], gamma, beta, ssb);
        // q = relu(bn(h)) @ W2 + b2 — R10 structure, split-K x8 (occupancy fix)
        k_gemm2d<<<dim3(E_DIM / 128, B_ROWS / 64, 8), 256, 0, stream>>>(
            h, W2T, qs[v], b2, ssb, B_ROWS, E_DIM, H_DIM);
    }

    // fused row-norm + transpose + cast of p1,q2,p2,q1 (into h's space)
    k_ntc<<<dim3(B_ROWS / 32, 4), 256, 0, stream>>>(
        p1, q2, p2, q1, p1T, q2T, p2T, q1T);

    k_gram<<<dim3(4, 4, 2 * GKS), 256, 0, stream>>>(p1T, q2T, p2T, q1T, Ma, Mb);
    k_m2<<<dim3(16, 16, 2), 256, 0, stream>>>(Ma, Mb, M2a, M2b);
    k_traces2<<<dim3(8, 8, 2), 256, 0, stream>>>(Ma, M2a, Mb, M2b, lam, out);
}

// Round 4
// 361.620 us; speedup vs baseline: 1.1016x; 1.0369x over previous
//
#include <hip/hip_runtime.h>

// Problem constants (fixed by reference)
#define B_ROWS 8192
#define E_DIM  256
#define H_DIM  4096

typedef __attribute__((ext_vector_type(8))) short short8;
typedef __attribute__((ext_vector_type(4))) float f32x4;

typedef __attribute__((address_space(1))) const void* gas1_t;
typedef __attribute__((address_space(3))) void*       las3_t;

__device__ __forceinline__ float b2f(unsigned short s) {
    return __uint_as_float(((unsigned)s) << 16);
}
__device__ __forceinline__ unsigned short f2b(float f) {
    unsigned u = __float_as_uint(f);
    u += 0x7fffu + ((u >> 16) & 1u);   // RNE
    return (unsigned short)(u >> 16);
}

// HW packed f32->bf16 convert (1 instr for 2 elems vs 4 VALU ops each).
// GEMM2 A-path only; absmax bit-identical (7.63e-6) across R16/R17/R18.
__device__ __forceinline__ unsigned cvt_pk_bf16(float lo, float hi) {
    unsigned r;
    asm("v_cvt_pk_bf16_f32 %0, %1, %2" : "=v"(r) : "v"(lo), "v"(hi));
    return r;
}

// LDS swizzle for BK=32 (64B rows, 4x16B slots): slot' = slot ^ ((row>>1)&3)
// -> ds_read_b128 fragment reads are 2-way (free, m136) instead of 8-way.
__device__ __forceinline__ int swz(int row, int slot) {
    return slot ^ ((row >> 1) & 3);
}

// ---------------------------------------------------------------------------
// Transpose + cast f32 [R,C] -> bf16 [C,R]
__global__ void k_transpose_cast(const float* __restrict__ in,
                                 unsigned short* __restrict__ out,
                                 int R, int C) {
    __shared__ float tile[32][33];
    const int c0 = blockIdx.x * 32, r0 = blockIdx.y * 32;
    const int tx = threadIdx.x & 31, ty = threadIdx.x >> 5;  // ty 0..7
#pragma unroll
    for (int j = 0; j < 4; ++j)
        tile[ty * 4 + j][tx] = in[(size_t)(r0 + ty * 4 + j) * C + c0 + tx];
    __syncthreads();
#pragma unroll
    for (int j = 0; j < 4; ++j)
        out[(size_t)(c0 + ty * 4 + j) * R + r0 + tx] = f2b(tile[tx][ty * 4 + j]);
}

// ---------------------------------------------------------------------------
// Cast f32 -> bf16, 4 elems/thread.
__global__ void k_cast_bf16(const float* __restrict__ in,
                            unsigned short* __restrict__ out, int n4) {
    int i = blockIdx.x * blockDim.x + threadIdx.x;
    if (i < n4) {
        float4 v = ((const float4*)in)[i];
        ushort4 o;
        o.x = f2b(v.x); o.y = f2b(v.y); o.z = f2b(v.z); o.w = f2b(v.w);
        ((ushort4*)out)[i] = o;
    }
}

// ---------------------------------------------------------------------------
// GEMM1 (R10 proven): h[M,N] = A[M,K] * Bt[N,K]^T, bf16 out + fused col stats.
// BM=BN=128, BK=32, swizzled global_load_lds staging. grid (N/128, M/128).
__global__ __launch_bounds__(256) void k_gemm1(
    const unsigned short* __restrict__ A, const unsigned short* __restrict__ Bt,
    unsigned short* __restrict__ Cout,
    float* __restrict__ cs, float* __restrict__ cs2,
    int M, int N, int K) {
    constexpr int BK = 32, BM = 128, BN = 128;
    constexpr int MI = 4, NI = 4;
    __shared__ __align__(16) short As[BM * BK];
    __shared__ __align__(16) short Bs[BN * BK];

    const int t = threadIdx.x;
    const int lane = t & 63, wv = t >> 6;
    const int wr = wv >> 1, wc = wv & 1;
    const int l15 = lane & 15, quad = lane >> 4;
    const int m0 = blockIdx.y * BM, n0 = blockIdx.x * BN;

    f32x4 acc[MI][NI] = {};

    for (int k0 = 0; k0 < K; k0 += BK) {
#pragma unroll
        for (int q = 0; q < 2; ++q) {
            int u = q * 256 + t;
            int row = u >> 2, kc = swz(row, u & 3);
            const short* gp = (const short*)A + (size_t)(m0 + row) * K + k0 + kc * 8;
            short* lp = As + (size_t)(q * 256 + (wv << 6)) * 8;  // wave-uniform base
            __builtin_amdgcn_global_load_lds((gas1_t)gp, (las3_t)lp, 16, 0, 0);
        }
#pragma unroll
        for (int q = 0; q < 2; ++q) {
            int u = q * 256 + t;
            int row = u >> 2, kc = swz(row, u & 3);
            const short* gp = (const short*)Bt + (size_t)(n0 + row) * K + k0 + kc * 8;
            short* lp = Bs + (size_t)(q * 256 + (wv << 6)) * 8;
            __builtin_amdgcn_global_load_lds((gas1_t)gp, (las3_t)lp, 16, 0, 0);
        }
        __syncthreads();

        short8 af[MI], bfr[NI];
#pragma unroll
        for (int mi = 0; mi < MI; ++mi) {
            int row = wr * 64 + mi * 16 + l15;
            af[mi] = *(const short8*)(As + row * BK + (swz(row, quad) << 3));
        }
#pragma unroll
        for (int ni = 0; ni < NI; ++ni) {
            int row = wc * 64 + ni * 16 + l15;
            bfr[ni] = *(const short8*)(Bs + row * BK + (swz(row, quad) << 3));
        }
#pragma unroll
        for (int mi = 0; mi < MI; ++mi)
#pragma unroll
            for (int ni = 0; ni < NI; ++ni)
                acc[mi][ni] = __builtin_amdgcn_mfma_f32_16x16x32_bf16(
                    af[mi], bfr[ni], acc[mi][ni], 0, 0, 0);
        __syncthreads();
    }

    // epilogue: C/D layout col=lane&15, row=quad*4+reg (measured m89)
#pragma unroll
    for (int ni = 0; ni < NI; ++ni) {
        float s = 0.f, s2 = 0.f;
#pragma unroll
        for (int mi = 0; mi < MI; ++mi)
#pragma unroll
            for (int r = 0; r < 4; ++r) {
                int row = m0 + wr * 64 + mi * 16 + quad * 4 + r;
                int col = n0 + wc * 64 + ni * 16 + l15;
                float v = acc[mi][ni][r];
                Cout[(size_t)row * N + col] = f2b(v);
                s += v; s2 += v * v;
            }
        s  += __shfl_xor(s, 16);  s  += __shfl_xor(s, 32);
        s2 += __shfl_xor(s2, 16); s2 += __shfl_xor(s2, 32);
        if (quad == 0) {
            int col = n0 + wc * 64 + ni * 16 + l15;
            atomicAdd(&cs[col], s);
            atomicAdd(&cs2[col], s2);
        }
    }
}

// BN scale/shift packed as bf16 pair: ssb[k] = f2b(scale)<<16 | f2b(shift)
// (bf16 params verified numerically R6/R9/R10/R14: absmax 7.6e-6 vs 2e-5 thr)
__global__ void k_bnprep(const float* __restrict__ sum, const float* __restrict__ sumsq,
                         const float* __restrict__ gamma, const float* __restrict__ beta,
                         unsigned* __restrict__ ssb) {
    int j = blockIdx.x * 256 + threadIdx.x;
    float mu = sum[j] * (1.f / B_ROWS);
    float var = sumsq[j] * (1.f / B_ROWS) - mu * mu;
    float sc = gamma[j] * rsqrtf(var + 1e-5f);
    float sh = beta[j] - mu * sc;
    ssb[j] = ((unsigned)f2b(sc) << 16) | (unsigned)f2b(sh);
}

__device__ __forceinline__ short8 bnrelu8(uint4 hv, uint4 sa, uint4 sb) {
    const unsigned short* hu = (const unsigned short*)&hv;
    const unsigned* wa = (const unsigned*)&sa;
    const unsigned* wb = (const unsigned*)&sb;
    float f[8];
#pragma unroll
    for (int j = 0; j < 8; ++j) {
        unsigned w = j < 4 ? wa[j] : wb[j - 4];
        float sc = __uint_as_float(w & 0xffff0000u);
        float sh = __uint_as_float(w << 16);
        f[j] = fmaxf(b2f(hu[j]) * sc + sh, 0.f);
    }
    union { unsigned u[4]; short8 s; } o;
#pragma unroll
    for (int j = 0; j < 4; ++j) o.u[j] = cvt_pk_bf16(f[2 * j], f[2 * j + 1]);
    return o.s;
}

// ---------------------------------------------------------------------------
// GEMM2 (R19): R10's double-buffered structure, split-K x4 (R18's x8 cost
// +50MB traffic), PLUS 2-deep prefetch of the h operand only.
// Theory: h is a 64MB HBM stream (~900cy miss latency); R10's 1-iter
// prefetch window (~200cy) exposed ~600cy/iter at the bnrelu consume.
// ssb/W2T are L2-resident -> stay 1-deep. Loop unrolled x2 with NAMED
// register sets (h0/h1) so all buffer indices are compile-time (rule #20).
__global__ __launch_bounds__(256) void k_gemm2d(
    const unsigned short* __restrict__ A, const unsigned short* __restrict__ Bt,
    float* __restrict__ Cout, const float* __restrict__ bias,
    const unsigned* __restrict__ ssb,
    int M, int N, int K) {
    constexpr int BK = 32, BM = 64, BN = 128;
    constexpr int MI = 2, NI = 4;
    __shared__ __align__(16) short As[2][BM * BK];   // 2 x 4 KB
    __shared__ __align__(16) short Bs[2][BN * BK];   // 2 x 8 KB

    const int t = threadIdx.x;
    const int lane = t & 63, wv = t >> 6;
    const int wr = wv >> 1, wc = wv & 1;
    const int l15 = lane & 15, quad = lane >> 4;
    const int m0 = blockIdx.y * BM, n0 = blockIdx.x * BN;

    const int Kc = K / gridDim.z;
    const int kbeg = blockIdx.z * Kc;
    const int ITERS = Kc / BK;             // 32 (even)

    const int arow = t >> 2, akc = t & 3;
    const unsigned short* hp = A + (size_t)(m0 + arow) * K + akc * 8;
    const unsigned* ssp = ssb + akc * 8;
    const int awoff = arow * BK + (swz(arow, akc) << 3);

    const unsigned short* bp0 = Bt + (size_t)(n0 + arow) * K + akc * 8;
    const unsigned short* bp1 = Bt + (size_t)(n0 + 64 + arow) * K + akc * 8;
    const int bwoff0 = arow * BK + (swz(arow, akc) << 3);
    const int bwoff1 = (64 + arow) * BK + (swz(64 + arow, akc) << 3);

    f32x4 acc[MI][NI] = {};

    // h: 2-deep (h0 for even iters, h1 for odd); rest 1-deep.
    uint4 h0 = *(const uint4*)(hp + kbeg);
    uint4 h1 = *(const uint4*)(hp + kbeg + BK);
    uint4 sa = *(const uint4*)(ssp + kbeg);
    uint4 sb = *(const uint4*)(ssp + kbeg + 4);
    uint4 b0 = *(const uint4*)(bp0 + kbeg);
    uint4 b1 = *(const uint4*)(bp1 + kbeg);

    for (int i = 0; i < ITERS; i += 2) {
        // ================= even iter (buffer 0, consumes h0) =================
        {
            short* Ab = As[0];
            short* Bb = Bs[0];
            *(short8*)(Ab + awoff) = bnrelu8(h0, sa, sb);
            *(uint4*)(Bb + bwoff0) = b0;
            *(uint4*)(Bb + bwoff1) = b1;
            __syncthreads();   // lgkm-only drain

            // issue h for iter i+2 (2-deep) and L2-residents for iter i+1
            const int k2 = (i + 2 < ITERS) ? kbeg + (i + 2) * BK : kbeg;
            h0 = *(const uint4*)(hp + k2);
            const int k1 = kbeg + (i + 1) * BK;   // i+1 < ITERS always (even ITERS)
            sa = *(const uint4*)(ssp + k1);
            sb = *(const uint4*)(ssp + k1 + 4);
            b0 = *(const uint4*)(bp0 + k1);
            b1 = *(const uint4*)(bp1 + k1);

            short8 af[MI], bfr[NI];
#pragma unroll
            for (int mi = 0; mi < MI; ++mi) {
                int row = wr * 32 + mi * 16 + l15;
                af[mi] = *(const short8*)(Ab + row * BK + (swz(row, quad) << 3));
            }
#pragma unroll
            for (int ni = 0; ni < NI; ++ni) {
                int row = wc * 64 + ni * 16 + l15;
                bfr[ni] = *(const short8*)(Bb + row * BK + (swz(row, quad) << 3));
            }
#pragma unroll
            for (int mi = 0; mi < MI; ++mi)
#pragma unroll
                for (int ni = 0; ni < NI; ++ni)
                    acc[mi][ni] = __builtin_amdgcn_mfma_f32_16x16x32_bf16(
                        af[mi], bfr[ni], acc[mi][ni], 0, 0, 0);
        }
        // ================= odd iter (buffer 1, consumes h1) ==================
        {
            short* Ab = As[1];
            short* Bb = Bs[1];
            *(short8*)(Ab + awoff) = bnrelu8(h1, sa, sb);
            *(uint4*)(Bb + bwoff0) = b0;
            *(uint4*)(Bb + bwoff1) = b1;
            __syncthreads();   // lgkm-only drain

            const int k3 = (i + 3 < ITERS) ? kbeg + (i + 3) * BK : kbeg;
            h1 = *(const uint4*)(hp + k3);
            const int k2 = (i + 2 < ITERS) ? kbeg + (i + 2) * BK : kbeg;
            sa = *(const uint4*)(ssp + k2);
            sb = *(const uint4*)(ssp + k2 + 4);
            b0 = *(const uint4*)(bp0 + k2);
            b1 = *(const uint4*)(bp1 + k2);

            short8 af[MI], bfr[NI];
#pragma unroll
            for (int mi = 0; mi < MI; ++mi) {
                int row = wr * 32 + mi * 16 + l15;
                af[mi] = *(const short8*)(Ab + row * BK + (swz(row, quad) << 3));
            }
#pragma unroll
            for (int ni = 0; ni < NI; ++ni) {
                int row = wc * 64 + ni * 16 + l15;
                bfr[ni] = *(const short8*)(Bb + row * BK + (swz(row, quad) << 3));
            }
#pragma unroll
            for (int mi = 0; mi < MI; ++mi)
#pragma unroll
                for (int ni = 0; ni < NI; ++ni)
                    acc[mi][ni] = __builtin_amdgcn_mfma_f32_16x16x32_bf16(
                        af[mi], bfr[ni], acc[mi][ni], 0, 0, 0);
        }
    }

#pragma unroll
    for (int mi = 0; mi < MI; ++mi)
#pragma unroll
        for (int ni = 0; ni < NI; ++ni)
#pragma unroll
            for (int r = 0; r < 4; ++r) {
                int row = m0 + wr * 32 + mi * 16 + quad * 4 + r;
                int col = n0 + wc * 64 + ni * 16 + l15;
                float v = acc[mi][ni][r];
                if (blockIdx.z == 0) v += bias[col];
                atomicAdd(&Cout[(size_t)row * N + col], v);
            }
}

// ---------------------------------------------------------------------------
// Fused norm + transpose + cast (R14-proven): per 32-row slab of X [8192,256]
// f32: load to LDS, row inv-norms, write XT [256,8192] bf16 normalized.
// grid (B/32, 4), block 256.
__global__ __launch_bounds__(256) void k_ntc(
    const float* __restrict__ x0, const float* __restrict__ x1,
    const float* __restrict__ x2, const float* __restrict__ x3,
    unsigned short* __restrict__ o0, unsigned short* __restrict__ o1,
    unsigned short* __restrict__ o2, unsigned short* __restrict__ o3) {
    const int z = blockIdx.y;
    const float* x = z == 0 ? x0 : z == 1 ? x1 : z == 2 ? x2 : x3;
    unsigned short* out = z == 0 ? o0 : z == 1 ? o1 : z == 2 ? o2 : o3;

    __shared__ float tile[32][264];
    __shared__ float red[32][8];
    __shared__ float invs[32];
    const int t = threadIdx.x;
    const int r0 = blockIdx.x * 32;

#pragma unroll
    for (int i = 0; i < 8; ++i) {
        int u = i * 256 + t;
        int row = u >> 6, cp = (u & 63) * 4;
        float4 v = *(const float4*)(x + (size_t)(r0 + row) * E_DIM + cp);
        *(float4*)&tile[row][cp] = v;
    }
    __syncthreads();
    {
        int row = t >> 3, cg = (t & 7) * 32;
        float s = 0.f;
#pragma unroll
        for (int j = 0; j < 32; ++j) { float v = tile[row][cg + j]; s += v * v; }
        red[row][t & 7] = s;
    }
    __syncthreads();
    if (t < 32) {
        float s = 0.f;
#pragma unroll
        for (int j = 0; j < 8; ++j) s += red[t][j];
        invs[t] = 1.f / fmaxf(sqrtf(s), 1e-12f);
    }
    __syncthreads();
    {
        int row = t & 31, cb = (t >> 5) * 32;
        float inv = invs[row];
#pragma unroll
        for (int j = 0; j < 32; ++j) {
            int c = cb + j;
            out[(size_t)c * B_ROWS + r0 + row] = f2b(tile[row][c] * inv);
        }
    }
}

// ---------------------------------------------------------------------------
// Gram via MFMA: Mout[a,b] += sum_k AT[a,k]*BT[b,k], AT/BT bf16 [256,8192].
// BM=BN=64, BK=32, swizzled staging, split-K x16; grid (4,4,32).
#define GKS 16
__global__ __launch_bounds__(256) void k_gram(
    const unsigned short* __restrict__ p1T, const unsigned short* __restrict__ q2T,
    const unsigned short* __restrict__ p2T, const unsigned short* __restrict__ q1T,
    float* __restrict__ Ma, float* __restrict__ Mb) {
    constexpr int BK = 32;
    const int mec = blockIdx.z >> 4, kz = blockIdx.z & 15;
    const unsigned short* A = mec ? p2T : p1T;
    const unsigned short* Bt = mec ? q1T : q2T;
    float* Mout = mec ? Mb : Ma;

    __shared__ __align__(16) short As[64 * BK];
    __shared__ __align__(16) short Bs[64 * BK];

    const int t = threadIdx.x;
    const int lane = t & 63, wv = t >> 6;
    const int wr = wv >> 1, wc = wv & 1;
    const int l15 = lane & 15, quad = lane >> 4;
    const int m0 = blockIdx.y * 64, n0 = blockIdx.x * 64;
    const int kbeg = kz * (B_ROWS / GKS);

    f32x4 acc[2][2] = {};

    for (int k0 = kbeg; k0 < kbeg + B_ROWS / GKS; k0 += BK) {
        {
            int row = t >> 2, kc = swz(row, t & 3);
            const short* gpa = (const short*)A + (size_t)(m0 + row) * B_ROWS + k0 + kc * 8;
            short* lpa = As + (size_t)(wv << 6) * 8;
            __builtin_amdgcn_global_load_lds((gas1_t)gpa, (las3_t)lpa, 16, 0, 0);
            const short* gpb = (const short*)Bt + (size_t)(n0 + row) * B_ROWS + k0 + kc * 8;
            short* lpb = Bs + (size_t)(wv << 6) * 8;
            __builtin_amdgcn_global_load_lds((gas1_t)gpb, (las3_t)lpb, 16, 0, 0);
        }
        __syncthreads();

        short8 af[2], bfr[2];
#pragma unroll
        for (int mi = 0; mi < 2; ++mi) {
            int row = wr * 32 + mi * 16 + l15;
            af[mi] = *(const short8*)(As + row * BK + (swz(row, quad) << 3));
        }
#pragma unroll
        for (int ni = 0; ni < 2; ++ni) {
            int row = wc * 32 + ni * 16 + l15;
            bfr[ni] = *(const short8*)(Bs + row * BK + (swz(row, quad) << 3));
        }
#pragma unroll
        for (int mi = 0; mi < 2; ++mi)
#pragma unroll
            for (int ni = 0; ni < 2; ++ni)
                acc[mi][ni] = __builtin_amdgcn_mfma_f32_16x16x32_bf16(
                    af[mi], bfr[ni], acc[mi][ni], 0, 0, 0);
        __syncthreads();
    }

#pragma unroll
    for (int mi = 0; mi < 2; ++mi)
#pragma unroll
        for (int ni = 0; ni < 2; ++ni)
#pragma unroll
            for (int r = 0; r < 4; ++r) {
                int row = m0 + wr * 32 + mi * 16 + quad * 4 + r;
                int col = n0 + wc * 32 + ni * 16 + l15;
                atomicAdd(&Mout[(size_t)row * E_DIM + col], acc[mi][ni][r]);
            }
}

// M2 = M*M (256x256). grid (16,16,2) block 256.
__global__ void k_m2(const float* __restrict__ Ma, const float* __restrict__ Mb,
                     float* __restrict__ M2a, float* __restrict__ M2b) {
    const float* M = blockIdx.z ? Mb : Ma;
    float* M2 = blockIdx.z ? M2b : M2a;
    int b = blockIdx.x * 16 + (threadIdx.x & 15);
    int a = blockIdx.y * 16 + (threadIdx.x >> 4);
    float s = 0.f;
    for (int k = 0; k < E_DIM; ++k) s += M[a * E_DIM + k] * M[k * E_DIM + b];
    M2[a * E_DIM + b] = s;
}

// ---------------------------------------------------------------------------
// Traces, tiled multi-block: grid (8,8,2), block 256.
__global__ __launch_bounds__(256) void k_traces2(
    const float* __restrict__ Ma, const float* __restrict__ M2a,
    const float* __restrict__ Mb, const float* __restrict__ M2b,
    const float* __restrict__ lam, float* __restrict__ out) {
    const float* M  = blockIdx.z ? Mb  : Ma;
    const float* M2 = blockIdx.z ? M2b : M2a;
    const int i0 = blockIdx.y * 32, j0 = blockIdx.x * 32;
    const int t = threadIdx.x, col = t & 31, row = t >> 5;  // row 0..7

    __shared__ float A[32][33], Bt[32][33], A2[32][33], B2[32][33];
#pragma unroll
    for (int r = 0; r < 4; ++r) {
        int rr = r * 8 + row;
        A [rr][col] = M [(i0 + rr) * E_DIM + j0 + col];
        Bt[rr][col] = M [(j0 + rr) * E_DIM + i0 + col];
        A2[rr][col] = M2[(i0 + rr) * E_DIM + j0 + col];
        B2[rr][col] = M2[(j0 + rr) * E_DIM + i0 + col];
    }
    __syncthreads();

    float lamv = lam[0];
    float il = 1.f / lamv;
    float F = -0.5f * lamv * (1.f / B_ROWS);  // -0.5*lam/B
    float c1 = F * il;
    float c2 = -F * 0.5f * il * il;
    float c3 = F * (1.f / 3.f) * il * il * il;
    float c4 = -F * 0.25f * il * il * il * il;

    float s = 0.f;
#pragma unroll
    for (int r = 0; r < 4; ++r) {
        int rr = r * 8 + row;
        float mij = A[rr][col], mji = Bt[col][rr];
        float m2ij = A2[rr][col], m2ji = B2[col][rr];
        s += c2 * mij * mji + c3 * m2ij * mji + c4 * m2ij * m2ji;
        if (i0 + rr == j0 + col) s += c1 * mij;
    }
#pragma unroll
    for (int o = 32; o; o >>= 1) s += __shfl_down(s, o);
    __shared__ float red[4];
    if ((t & 63) == 0) red[t >> 6] = s;
    __syncthreads();
    if (t == 0) atomicAdd(out, red[0] + red[1] + red[2] + red[3]);
}

// ---------------------------------------------------------------------------
extern "C" void kernel_launch(void* const* d_in, const int* in_sizes, int n_in,
                              void* d_out, int out_size, void* d_ws, size_t ws_size,
                              hipStream_t stream) {
    const float* z1 = (const float*)d_in[0];
    const float* z2 = (const float*)d_in[1];
    const float* p1 = (const float*)d_in[2];
    const float* p2 = (const float*)d_in[3];
    const float* W1 = (const float*)d_in[4];
    const float* gamma = (const float*)d_in[5];
    const float* beta = (const float*)d_in[6];
    const float* W2 = (const float*)d_in[7];
    const float* b2 = (const float*)d_in[8];
    const float* lam = (const float*)d_in[9];
    float* out = (float*)d_out;
    char* ws = (char*)d_ws;

    // workspace layout (~89 MB)
    size_t off = 0;
    auto alloc = [&](size_t bytes) { size_t o = off; off += (bytes + 255) & ~(size_t)255; return o; };
    unsigned short* W1T = (unsigned short*)(ws + alloc((size_t)E_DIM * H_DIM * 2));  // [H,E] bf16
    unsigned short* W2T = (unsigned short*)(ws + alloc((size_t)H_DIM * E_DIM * 2));  // [E,H] bf16
    unsigned short* zb  = (unsigned short*)(ws + alloc((size_t)B_ROWS * E_DIM * 2));
    unsigned short* h   = (unsigned short*)(ws + alloc((size_t)B_ROWS * H_DIM * 2));
    // q1,q2,Ma,Mb contiguous -> single memset
    float* q1 = (float*)(ws + alloc((size_t)B_ROWS * E_DIM * 4));
    float* q2 = (float*)(ws + alloc((size_t)B_ROWS * E_DIM * 4));
    float* Ma  = (float*)(ws + alloc((size_t)E_DIM * E_DIM * 4));
    float* Mb  = (float*)(ws + alloc((size_t)E_DIM * E_DIM * 4));
    float* M2a = (float*)(ws + alloc((size_t)E_DIM * E_DIM * 4));
    float* M2b = (float*)(ws + alloc((size_t)E_DIM * E_DIM * 4));
    // two colsum sets (one per view), contiguous -> single memset
    float* cs0 = (float*)(ws + alloc(H_DIM * 4));
    float* cs0q = (float*)(ws + alloc(H_DIM * 4));
    float* cs1 = (float*)(ws + alloc(H_DIM * 4));
    float* cs1q = (float*)(ws + alloc(H_DIM * 4));
    unsigned* ssb = (unsigned*)(ws + alloc(H_DIM * 4));

    // transposed normalized bf16 views alias into h (free after last GEMM2)
    const size_t TSZ = (size_t)E_DIM * B_ROWS;  // 2M elements each
    unsigned short* p1T = h;
    unsigned short* q2T = h + TSZ;
    unsigned short* p2T = h + 2 * TSZ;
    unsigned short* q1T = h + 3 * TSZ;

    // zero accumulation targets (3 memsets total)
    hipMemsetAsync(out, 0, sizeof(float), stream);
    hipMemsetAsync(q1, 0, ((size_t)2 * B_ROWS * E_DIM + 2 * E_DIM * E_DIM) * 4, stream);
    hipMemsetAsync(cs0, 0, (size_t)4 * H_DIM * 4, stream);

    // weight transposes (k-contiguous operands for MFMA)
    k_transpose_cast<<<dim3(H_DIM / 32, E_DIM / 32), 256, 0, stream>>>(W1, W1T, E_DIM, H_DIM);
    k_transpose_cast<<<dim3(E_DIM / 32, H_DIM / 32), 256, 0, stream>>>(W2, W2T, H_DIM, E_DIM);

    const float* zs[2] = {z1, z2};
    float* qs[2] = {q1, q2};
    float* css[2] = {cs0, cs1};
    float* cssq[2] = {cs0q, cs1q};
    for (int v = 0; v < 2; ++v) {
        k_cast_bf16<<<dim3(B_ROWS * E_DIM / 4 / 256), 256, 0, stream>>>(zs[v], zb, B_ROWS * E_DIM / 4);
        // h = z @ W1, with fused column stats
        k_gemm1<<<dim3(H_DIM / 128, B_ROWS / 128), 256, 0, stream>>>(
            zb, W1T, h, css[v], cssq[v], B_ROWS, H_DIM, E_DIM);
        k_bnprep<<<dim3(H_DIM / 256), 256, 0, stream>>>(css[v], cssq[v], gamma, beta, ssb);
        // q = relu(bn(h)) @ W2 + b2 — R10 structure + 2-deep h prefetch, split-K x4
        k_gemm2d<<<dim3(E_DIM / 128, B_ROWS / 64, 4), 256, 0, stream>>>(
            h, W2T, qs[v], b2, ssb, B_ROWS, E_DIM, H_DIM);
    }

    // fused row-norm + transpose + cast of p1,q2,p2,q1 (into h's space)
    k_ntc<<<dim3(B_ROWS / 32, 4), 256, 0, stream>>>(
        p1, q2, p2, q1, p1T, q2T, p2T, q1T);

    k_gram<<<dim3(4, 4, 2 * GKS), 256, 0, stream>>>(p1T, q2T, p2T, q1T, Ma, Mb);
    k_m2<<<dim3(16, 16, 2), 256, 0, stream>>>(Ma, Mb, M2a, M2b);
    k_traces2<<<dim3(8, 8, 2), 256, 0, stream>>>(Ma, M2a, Mb, M2b, lam, out);
}

// Round 5
// 340.223 us; speedup vs baseline: 1.1709x; 1.0629x over previous
//
#include <hip/hip_runtime.h>

// Problem constants (fixed by reference)
#define B_ROWS 8192
#define E_DIM  256
#define H_DIM  4096

typedef __attribute__((ext_vector_type(8))) short short8;
typedef __attribute__((ext_vector_type(4))) float f32x4;

typedef __attribute__((address_space(1))) const void* gas1_t;
typedef __attribute__((address_space(3))) void*       las3_t;

__device__ __forceinline__ float b2f(unsigned short s) {
    return __uint_as_float(((unsigned)s) << 16);
}
__device__ __forceinline__ unsigned short f2b(float f) {
    unsigned u = __float_as_uint(f);
    u += 0x7fffu + ((u >> 16) & 1u);   // RNE
    return (unsigned short)(u >> 16);
}

// HW packed f32->bf16 convert (1 instr for 2 elems vs 4 VALU ops each).
// GEMM2 A-path only; absmax bit-identical (7.63e-6) across R16-R19.
__device__ __forceinline__ unsigned cvt_pk_bf16(float lo, float hi) {
    unsigned r;
    asm("v_cvt_pk_bf16_f32 %0, %1, %2" : "=v"(r) : "v"(lo), "v"(hi));
    return r;
}

// LDS swizzle for BK=32 (64B rows, 4x16B slots): slot' = slot ^ ((row>>1)&3)
// -> ds_read_b128 fragment reads are 2-way (free, m136) instead of 8-way.
__device__ __forceinline__ int swz(int row, int slot) {
    return slot ^ ((row >> 1) & 3);
}

// ---------------------------------------------------------------------------
// Transpose + cast f32 [R,C] -> bf16 [C,R]
__global__ void k_transpose_cast(const float* __restrict__ in,
                                 unsigned short* __restrict__ out,
                                 int R, int C) {
    __shared__ float tile[32][33];
    const int c0 = blockIdx.x * 32, r0 = blockIdx.y * 32;
    const int tx = threadIdx.x & 31, ty = threadIdx.x >> 5;  // ty 0..7
#pragma unroll
    for (int j = 0; j < 4; ++j)
        tile[ty * 4 + j][tx] = in[(size_t)(r0 + ty * 4 + j) * C + c0 + tx];
    __syncthreads();
#pragma unroll
    for (int j = 0; j < 4; ++j)
        out[(size_t)(c0 + ty * 4 + j) * R + r0 + tx] = f2b(tile[tx][ty * 4 + j]);
}

// ---------------------------------------------------------------------------
// Cast f32 -> bf16, 4 elems/thread.
__global__ void k_cast_bf16(const float* __restrict__ in,
                            unsigned short* __restrict__ out, int n4) {
    int i = blockIdx.x * blockDim.x + threadIdx.x;
    if (i < n4) {
        float4 v = ((const float4*)in)[i];
        ushort4 o;
        o.x = f2b(v.x); o.y = f2b(v.y); o.z = f2b(v.z); o.w = f2b(v.w);
        ((ushort4*)out)[i] = o;
    }
}

// ---------------------------------------------------------------------------
// GEMM1 (R10 proven): h[M,N] = A[M,K] * Bt[N,K]^T, bf16 out + fused col stats.
// BM=BN=128, BK=32, swizzled global_load_lds staging. grid (N/128, M/128).
__global__ __launch_bounds__(256) void k_gemm1(
    const unsigned short* __restrict__ A, const unsigned short* __restrict__ Bt,
    unsigned short* __restrict__ Cout,
    float* __restrict__ cs, float* __restrict__ cs2,
    int M, int N, int K) {
    constexpr int BK = 32, BM = 128, BN = 128;
    constexpr int MI = 4, NI = 4;
    __shared__ __align__(16) short As[BM * BK];
    __shared__ __align__(16) short Bs[BN * BK];

    const int t = threadIdx.x;
    const int lane = t & 63, wv = t >> 6;
    const int wr = wv >> 1, wc = wv & 1;
    const int l15 = lane & 15, quad = lane >> 4;
    const int m0 = blockIdx.y * BM, n0 = blockIdx.x * BN;

    f32x4 acc[MI][NI] = {};

    for (int k0 = 0; k0 < K; k0 += BK) {
#pragma unroll
        for (int q = 0; q < 2; ++q) {
            int u = q * 256 + t;
            int row = u >> 2, kc = swz(row, u & 3);
            const short* gp = (const short*)A + (size_t)(m0 + row) * K + k0 + kc * 8;
            short* lp = As + (size_t)(q * 256 + (wv << 6)) * 8;  // wave-uniform base
            __builtin_amdgcn_global_load_lds((gas1_t)gp, (las3_t)lp, 16, 0, 0);
        }
#pragma unroll
        for (int q = 0; q < 2; ++q) {
            int u = q * 256 + t;
            int row = u >> 2, kc = swz(row, u & 3);
            const short* gp = (const short*)Bt + (size_t)(n0 + row) * K + k0 + kc * 8;
            short* lp = Bs + (size_t)(q * 256 + (wv << 6)) * 8;
            __builtin_amdgcn_global_load_lds((gas1_t)gp, (las3_t)lp, 16, 0, 0);
        }
        __syncthreads();

        short8 af[MI], bfr[NI];
#pragma unroll
        for (int mi = 0; mi < MI; ++mi) {
            int row = wr * 64 + mi * 16 + l15;
            af[mi] = *(const short8*)(As + row * BK + (swz(row, quad) << 3));
        }
#pragma unroll
        for (int ni = 0; ni < NI; ++ni) {
            int row = wc * 64 + ni * 16 + l15;
            bfr[ni] = *(const short8*)(Bs + row * BK + (swz(row, quad) << 3));
        }
#pragma unroll
        for (int mi = 0; mi < MI; ++mi)
#pragma unroll
            for (int ni = 0; ni < NI; ++ni)
                acc[mi][ni] = __builtin_amdgcn_mfma_f32_16x16x32_bf16(
                    af[mi], bfr[ni], acc[mi][ni], 0, 0, 0);
        __syncthreads();
    }

    // epilogue: C/D layout col=lane&15, row=quad*4+reg (measured m89)
#pragma unroll
    for (int ni = 0; ni < NI; ++ni) {
        float s = 0.f, s2 = 0.f;
#pragma unroll
        for (int mi = 0; mi < MI; ++mi)
#pragma unroll
            for (int r = 0; r < 4; ++r) {
                int row = m0 + wr * 64 + mi * 16 + quad * 4 + r;
                int col = n0 + wc * 64 + ni * 16 + l15;
                float v = acc[mi][ni][r];
                Cout[(size_t)row * N + col] = f2b(v);
                s += v; s2 += v * v;
            }
        s  += __shfl_xor(s, 16);  s  += __shfl_xor(s, 32);
        s2 += __shfl_xor(s2, 16); s2 += __shfl_xor(s2, 32);
        if (quad == 0) {
            int col = n0 + wc * 64 + ni * 16 + l15;
            atomicAdd(&cs[col], s);
            atomicAdd(&cs2[col], s2);
        }
    }
}

// BN scale/shift packed as bf16 pair: ssb[k] = f2b(scale)<<16 | f2b(shift)
// (bf16 params verified numerically R6/R9/R10/R14: absmax 7.6e-6 vs 2e-5 thr)
__global__ void k_bnprep(const float* __restrict__ sum, const float* __restrict__ sumsq,
                         const float* __restrict__ gamma, const float* __restrict__ beta,
                         unsigned* __restrict__ ssb) {
    int j = blockIdx.x * 256 + threadIdx.x;
    float mu = sum[j] * (1.f / B_ROWS);
    float var = sumsq[j] * (1.f / B_ROWS) - mu * mu;
    float sc = gamma[j] * rsqrtf(var + 1e-5f);
    float sh = beta[j] - mu * sc;
    ssb[j] = ((unsigned)f2b(sc) << 16) | (unsigned)f2b(sh);
}

__device__ __forceinline__ short8 bnrelu8(uint4 hv, uint4 sa, uint4 sb) {
    const unsigned short* hu = (const unsigned short*)&hv;
    const unsigned* wa = (const unsigned*)&sa;
    const unsigned* wb = (const unsigned*)&sb;
    float f[8];
#pragma unroll
    for (int j = 0; j < 8; ++j) {
        unsigned w = j < 4 ? wa[j] : wb[j - 4];
        float sc = __uint_as_float(w & 0xffff0000u);
        float sh = __uint_as_float(w << 16);
        f[j] = fmaxf(b2f(hu[j]) * sc + sh, 0.f);
    }
    union { unsigned u[4]; short8 s; } o;
#pragma unroll
    for (int j = 0; j < 4; ++j) o.u[j] = cvt_pk_bf16(f[2 * j], f[2 * j + 1]);
    return o.s;
}

// ---------------------------------------------------------------------------
// GEMM2 (R20): R10's EXACT loop body & 1-deep prefetch (the compiler schedule
// R16-R19 could never beat), geometry change only: BM 64->32 doubles the grid
// to 2048 blocks = 8 blocks/CU (LDS 20KB x8 = 160KB exact; launch_bounds
// (256,8) caps VGPR at 64 so all 32 waves/CU are resident). Theory: R10 was
// grid-capped at 4 blocks/CU; R18 proved occupancy->throughput (+16%/byte)
// but paid +50MB traffic; this gets the waves with ZERO traffic delta.
// A-staging (32x32 tile = 128 units) runs on waves 0-1 (wave-uniform).
__global__ __launch_bounds__(256, 8) void k_gemm2d(
    const unsigned short* __restrict__ A, const unsigned short* __restrict__ Bt,
    float* __restrict__ Cout, const float* __restrict__ bias,
    const unsigned* __restrict__ ssb,
    int M, int N, int K) {
    constexpr int BK = 32, BM = 32, BN = 128;
    constexpr int NI = 4;
    __shared__ __align__(16) short As[2][BM * BK];   // 2 x 2 KB
    __shared__ __align__(16) short Bs[2][BN * BK];   // 2 x 8 KB

    const int t = threadIdx.x;
    const int lane = t & 63, wv = t >> 6;
    const int wr = wv >> 1, wc = wv & 1;             // 2x2 wave grid, tile 16x64
    const int l15 = lane & 15, quad = lane >> 4;
    const int m0 = blockIdx.y * BM, n0 = blockIdx.x * BN;

    const int Kc = K / gridDim.z;
    const int kbeg = blockIdx.z * Kc;
    const int ITERS = Kc / BK;

    const bool aw = (t < 128);                       // waves 0-1 stage A
    const int arow = (t & 127) >> 2, akc = t & 3;    // A: 32 rows x 4 slots
    const unsigned short* hp = A + (size_t)(m0 + arow) * K + akc * 8;
    const unsigned* ssp = ssb + akc * 8;
    const int awoff = arow * BK + (swz(arow, akc) << 3);

    const int brow = t >> 2;                         // B: rows 0..63 (+64)
    const unsigned short* bp0 = Bt + (size_t)(n0 + brow) * K + akc * 8;
    const unsigned short* bp1 = Bt + (size_t)(n0 + 64 + brow) * K + akc * 8;
    const int bwoff0 = brow * BK + (swz(brow, akc) << 3);
    const int bwoff1 = (64 + brow) * BK + (swz(64 + brow, akc) << 3);

    f32x4 acc[NI] = {};

    uint4 hreg = {}, sa = {}, sb = {};
    if (aw) {
        hreg = *(const uint4*)(hp + kbeg);
        sa = *(const uint4*)(ssp + kbeg);
        sb = *(const uint4*)(ssp + kbeg + 4);
    }
    uint4 b0 = *(const uint4*)(bp0 + kbeg);
    uint4 b1 = *(const uint4*)(bp1 + kbeg);

    for (int i = 0; i < ITERS; ++i) {
        const int k0 = kbeg + i * BK;
        short* Ab = As[i & 1];
        short* Bb = Bs[i & 1];

        if (aw) *(short8*)(Ab + awoff) = bnrelu8(hreg, sa, sb);
        *(uint4*)(Bb + bwoff0) = b0;
        *(uint4*)(Bb + bwoff1) = b1;
        __syncthreads();   // lgkm-only drain

        const int kn = (i + 1 < ITERS) ? k0 + BK : kbeg;
        if (aw) {
            hreg = *(const uint4*)(hp + kn);
            sa = *(const uint4*)(ssp + kn);
            sb = *(const uint4*)(ssp + kn + 4);
        }
        b0 = *(const uint4*)(bp0 + kn);
        b1 = *(const uint4*)(bp1 + kn);

        short8 af, bfr[NI];
        {
            int row = wr * 16 + l15;
            af = *(const short8*)(Ab + row * BK + (swz(row, quad) << 3));
        }
#pragma unroll
        for (int ni = 0; ni < NI; ++ni) {
            int row = wc * 64 + ni * 16 + l15;
            bfr[ni] = *(const short8*)(Bb + row * BK + (swz(row, quad) << 3));
        }
#pragma unroll
        for (int ni = 0; ni < NI; ++ni)
            acc[ni] = __builtin_amdgcn_mfma_f32_16x16x32_bf16(
                af, bfr[ni], acc[ni], 0, 0, 0);
    }

#pragma unroll
    for (int ni = 0; ni < NI; ++ni)
#pragma unroll
        for (int r = 0; r < 4; ++r) {
            int row = m0 + wr * 16 + quad * 4 + r;
            int col = n0 + wc * 64 + ni * 16 + l15;
            float v = acc[ni][r];
            if (blockIdx.z == 0) v += bias[col];
            atomicAdd(&Cout[(size_t)row * N + col], v);
        }
}

// ---------------------------------------------------------------------------
// Fused norm + transpose + cast (R14-proven): per 32-row slab of X [8192,256]
// f32: load to LDS, row inv-norms, write XT [256,8192] bf16 normalized.
// grid (B/32, 4), block 256.
__global__ __launch_bounds__(256) void k_ntc(
    const float* __restrict__ x0, const float* __restrict__ x1,
    const float* __restrict__ x2, const float* __restrict__ x3,
    unsigned short* __restrict__ o0, unsigned short* __restrict__ o1,
    unsigned short* __restrict__ o2, unsigned short* __restrict__ o3) {
    const int z = blockIdx.y;
    const float* x = z == 0 ? x0 : z == 1 ? x1 : z == 2 ? x2 : x3;
    unsigned short* out = z == 0 ? o0 : z == 1 ? o1 : z == 2 ? o2 : o3;

    __shared__ float tile[32][264];
    __shared__ float red[32][8];
    __shared__ float invs[32];
    const int t = threadIdx.x;
    const int r0 = blockIdx.x * 32;

#pragma unroll
    for (int i = 0; i < 8; ++i) {
        int u = i * 256 + t;
        int row = u >> 6, cp = (u & 63) * 4;
        float4 v = *(const float4*)(x + (size_t)(r0 + row) * E_DIM + cp);
        *(float4*)&tile[row][cp] = v;
    }
    __syncthreads();
    {
        int row = t >> 3, cg = (t & 7) * 32;
        float s = 0.f;
#pragma unroll
        for (int j = 0; j < 32; ++j) { float v = tile[row][cg + j]; s += v * v; }
        red[row][t & 7] = s;
    }
    __syncthreads();
    if (t < 32) {
        float s = 0.f;
#pragma unroll
        for (int j = 0; j < 8; ++j) s += red[t][j];
        invs[t] = 1.f / fmaxf(sqrtf(s), 1e-12f);
    }
    __syncthreads();
    {
        int row = t & 31, cb = (t >> 5) * 32;
        float inv = invs[row];
#pragma unroll
        for (int j = 0; j < 32; ++j) {
            int c = cb + j;
            out[(size_t)c * B_ROWS + r0 + row] = f2b(tile[row][c] * inv);
        }
    }
}

// ---------------------------------------------------------------------------
// Gram via MFMA: Mout[a,b] += sum_k AT[a,k]*BT[b,k], AT/BT bf16 [256,8192].
// BM=BN=64, BK=32, swizzled staging, split-K x16; grid (4,4,32).
#define GKS 16
__global__ __launch_bounds__(256) void k_gram(
    const unsigned short* __restrict__ p1T, const unsigned short* __restrict__ q2T,
    const unsigned short* __restrict__ p2T, const unsigned short* __restrict__ q1T,
    float* __restrict__ Ma, float* __restrict__ Mb) {
    constexpr int BK = 32;
    const int mec = blockIdx.z >> 4, kz = blockIdx.z & 15;
    const unsigned short* A = mec ? p2T : p1T;
    const unsigned short* Bt = mec ? q1T : q2T;
    float* Mout = mec ? Mb : Ma;

    __shared__ __align__(16) short As[64 * BK];
    __shared__ __align__(16) short Bs[64 * BK];

    const int t = threadIdx.x;
    const int lane = t & 63, wv = t >> 6;
    const int wr = wv >> 1, wc = wv & 1;
    const int l15 = lane & 15, quad = lane >> 4;
    const int m0 = blockIdx.y * 64, n0 = blockIdx.x * 64;
    const int kbeg = kz * (B_ROWS / GKS);

    f32x4 acc[2][2] = {};

    for (int k0 = kbeg; k0 < kbeg + B_ROWS / GKS; k0 += BK) {
        {
            int row = t >> 2, kc = swz(row, t & 3);
            const short* gpa = (const short*)A + (size_t)(m0 + row) * B_ROWS + k0 + kc * 8;
            short* lpa = As + (size_t)(wv << 6) * 8;
            __builtin_amdgcn_global_load_lds((gas1_t)gpa, (las3_t)lpa, 16, 0, 0);
            const short* gpb = (const short*)Bt + (size_t)(n0 + row) * B_ROWS + k0 + kc * 8;
            short* lpb = Bs + (size_t)(wv << 6) * 8;
            __builtin_amdgcn_global_load_lds((gas1_t)gpb, (las3_t)lpb, 16, 0, 0);
        }
        __syncthreads();

        short8 af[2], bfr[2];
#pragma unroll
        for (int mi = 0; mi < 2; ++mi) {
            int row = wr * 32 + mi * 16 + l15;
            af[mi] = *(const short8*)(As + row * BK + (swz(row, quad) << 3));
        }
#pragma unroll
        for (int ni = 0; ni < 2; ++ni) {
            int row = wc * 32 + ni * 16 + l15;
            bfr[ni] = *(const short8*)(Bs + row * BK + (swz(row, quad) << 3));
        }
#pragma unroll
        for (int mi = 0; mi < 2; ++mi)
#pragma unroll
            for (int ni = 0; ni < 2; ++ni)
                acc[mi][ni] = __builtin_amdgcn_mfma_f32_16x16x32_bf16(
                    af[mi], bfr[ni], acc[mi][ni], 0, 0, 0);
        __syncthreads();
    }

#pragma unroll
    for (int mi = 0; mi < 2; ++mi)
#pragma unroll
        for (int ni = 0; ni < 2; ++ni)
#pragma unroll
            for (int r = 0; r < 4; ++r) {
                int row = m0 + wr * 32 + mi * 16 + quad * 4 + r;
                int col = n0 + wc * 32 + ni * 16 + l15;
                atomicAdd(&Mout[(size_t)row * E_DIM + col], acc[mi][ni][r]);
            }
}

// M2 = M*M (256x256). grid (16,16,2) block 256.
__global__ void k_m2(const float* __restrict__ Ma, const float* __restrict__ Mb,
                     float* __restrict__ M2a, float* __restrict__ M2b) {
    const float* M = blockIdx.z ? Mb : Ma;
    float* M2 = blockIdx.z ? M2b : M2a;
    int b = blockIdx.x * 16 + (threadIdx.x & 15);
    int a = blockIdx.y * 16 + (threadIdx.x >> 4);
    float s = 0.f;
    for (int k = 0; k < E_DIM; ++k) s += M[a * E_DIM + k] * M[k * E_DIM + b];
    M2[a * E_DIM + b] = s;
}

// ---------------------------------------------------------------------------
// Traces, tiled multi-block: grid (8,8,2), block 256.
__global__ __launch_bounds__(256) void k_traces2(
    const float* __restrict__ Ma, const float* __restrict__ M2a,
    const float* __restrict__ Mb, const float* __restrict__ M2b,
    const float* __restrict__ lam, float* __restrict__ out) {
    const float* M  = blockIdx.z ? Mb  : Ma;
    const float* M2 = blockIdx.z ? M2b : M2a;
    const int i0 = blockIdx.y * 32, j0 = blockIdx.x * 32;
    const int t = threadIdx.x, col = t & 31, row = t >> 5;  // row 0..7

    __shared__ float A[32][33], Bt[32][33], A2[32][33], B2[32][33];
#pragma unroll
    for (int r = 0; r < 4; ++r) {
        int rr = r * 8 + row;
        A [rr][col] = M [(i0 + rr) * E_DIM + j0 + col];
        Bt[rr][col] = M [(j0 + rr) * E_DIM + i0 + col];
        A2[rr][col] = M2[(i0 + rr) * E_DIM + j0 + col];
        B2[rr][col] = M2[(j0 + rr) * E_DIM + i0 + col];
    }
    __syncthreads();

    float lamv = lam[0];
    float il = 1.f / lamv;
    float F = -0.5f * lamv * (1.f / B_ROWS);  // -0.5*lam/B
    float c1 = F * il;
    float c2 = -F * 0.5f * il * il;
    float c3 = F * (1.f / 3.f) * il * il * il;
    float c4 = -F * 0.25f * il * il * il * il;

    float s = 0.f;
#pragma unroll
    for (int r = 0; r < 4; ++r) {
        int rr = r * 8 + row;
        float mij = A[rr][col], mji = Bt[col][rr];
        float m2ij = A2[rr][col], m2ji = B2[col][rr];
        s += c2 * mij * mji + c3 * m2ij * mji + c4 * m2ij * m2ji;
        if (i0 + rr == j0 + col) s += c1 * mij;
    }
#pragma unroll
    for (int o = 32; o; o >>= 1) s += __shfl_down(s, o);
    __shared__ float red[4];
    if ((t & 63) == 0) red[t >> 6] = s;
    __syncthreads();
    if (t == 0) atomicAdd(out, red[0] + red[1] + red[2] + red[3]);
}

// ---------------------------------------------------------------------------
extern "C" void kernel_launch(void* const* d_in, const int* in_sizes, int n_in,
                              void* d_out, int out_size, void* d_ws, size_t ws_size,
                              hipStream_t stream) {
    const float* z1 = (const float*)d_in[0];
    const float* z2 = (const float*)d_in[1];
    const float* p1 = (const float*)d_in[2];
    const float* p2 = (const float*)d_in[3];
    const float* W1 = (const float*)d_in[4];
    const float* gamma = (const float*)d_in[5];
    const float* beta = (const float*)d_in[6];
    const float* W2 = (const float*)d_in[7];
    const float* b2 = (const float*)d_in[8];
    const float* lam = (const float*)d_in[9];
    float* out = (float*)d_out;
    char* ws = (char*)d_ws;

    // workspace layout (~89 MB)
    size_t off = 0;
    auto alloc = [&](size_t bytes) { size_t o = off; off += (bytes + 255) & ~(size_t)255; return o; };
    unsigned short* W1T = (unsigned short*)(ws + alloc((size_t)E_DIM * H_DIM * 2));  // [H,E] bf16
    unsigned short* W2T = (unsigned short*)(ws + alloc((size_t)H_DIM * E_DIM * 2));  // [E,H] bf16
    unsigned short* zb  = (unsigned short*)(ws + alloc((size_t)B_ROWS * E_DIM * 2));
    unsigned short* h   = (unsigned short*)(ws + alloc((size_t)B_ROWS * H_DIM * 2));
    // q1,q2,Ma,Mb contiguous -> single memset
    float* q1 = (float*)(ws + alloc((size_t)B_ROWS * E_DIM * 4));
    float* q2 = (float*)(ws + alloc((size_t)B_ROWS * E_DIM * 4));
    float* Ma  = (float*)(ws + alloc((size_t)E_DIM * E_DIM * 4));
    float* Mb  = (float*)(ws + alloc((size_t)E_DIM * E_DIM * 4));
    float* M2a = (float*)(ws + alloc((size_t)E_DIM * E_DIM * 4));
    float* M2b = (float*)(ws + alloc((size_t)E_DIM * E_DIM * 4));
    // two colsum sets (one per view), contiguous -> single memset
    float* cs0 = (float*)(ws + alloc(H_DIM * 4));
    float* cs0q = (float*)(ws + alloc(H_DIM * 4));
    float* cs1 = (float*)(ws + alloc(H_DIM * 4));
    float* cs1q = (float*)(ws + alloc(H_DIM * 4));
    unsigned* ssb = (unsigned*)(ws + alloc(H_DIM * 4));

    // transposed normalized bf16 views alias into h (free after last GEMM2)
    const size_t TSZ = (size_t)E_DIM * B_ROWS;  // 2M elements each
    unsigned short* p1T = h;
    unsigned short* q2T = h + TSZ;
    unsigned short* p2T = h + 2 * TSZ;
    unsigned short* q1T = h + 3 * TSZ;

    // zero accumulation targets (3 memsets total)
    hipMemsetAsync(out, 0, sizeof(float), stream);
    hipMemsetAsync(q1, 0, ((size_t)2 * B_ROWS * E_DIM + 2 * E_DIM * E_DIM) * 4, stream);
    hipMemsetAsync(cs0, 0, (size_t)4 * H_DIM * 4, stream);

    // weight transposes (k-contiguous operands for MFMA)
    k_transpose_cast<<<dim3(H_DIM / 32, E_DIM / 32), 256, 0, stream>>>(W1, W1T, E_DIM, H_DIM);
    k_transpose_cast<<<dim3(E_DIM / 32, H_DIM / 32), 256, 0, stream>>>(W2, W2T, H_DIM, E_DIM);

    const float* zs[2] = {z1, z2};
    float* qs[2] = {q1, q2};
    float* css[2] = {cs0, cs1};
    float* cssq[2] = {cs0q, cs1q};
    for (int v = 0; v < 2; ++v) {
        k_cast_bf16<<<dim3(B_ROWS * E_DIM / 4 / 256), 256, 0, stream>>>(zs[v], zb, B_ROWS * E_DIM / 4);
        // h = z @ W1, with fused column stats
        k_gemm1<<<dim3(H_DIM / 128, B_ROWS / 128), 256, 0, stream>>>(
            zb, W1T, h, css[v], cssq[v], B_ROWS, H_DIM, E_DIM);
        k_bnprep<<<dim3(H_DIM / 256), 256, 0, stream>>>(css[v], cssq[v], gamma, beta, ssb);
        // q = relu(bn(h)) @ W2 + b2 — R10 body, BM=32 -> 8 blocks/CU, split-K x4
        k_gemm2d<<<dim3(E_DIM / 128, B_ROWS / 32, 4), 256, 0, stream>>>(
            h, W2T, qs[v], b2, ssb, B_ROWS, E_DIM, H_DIM);
    }

    // fused row-norm + transpose + cast of p1,q2,p2,q1 (into h's space)
    k_ntc<<<dim3(B_ROWS / 32, 4), 256, 0, stream>>>(
        p1, q2, p2, q1, p1T, q2T, p2T, q1T);

    k_gram<<<dim3(4, 4, 2 * GKS), 256, 0, stream>>>(p1T, q2T, p2T, q1T, Ma, Mb);
    k_m2<<<dim3(16, 16, 2), 256, 0, stream>>>(Ma, Mb, M2a, M2b);
    k_traces2<<<dim3(8, 8, 2), 256, 0, stream>>>(Ma, M2a, Mb, M2b, lam, out);
}

// Round 6
// 339.802 us; speedup vs baseline: 1.1724x; 1.0012x over previous
//
#include <hip/hip_runtime.h>

// Problem constants (fixed by reference)
#define B_ROWS 8192
#define E_DIM  256
#define H_DIM  4096

typedef __attribute__((ext_vector_type(8))) short short8;
typedef __attribute__((ext_vector_type(4))) float f32x4;

typedef __attribute__((address_space(1))) const void* gas1_t;
typedef __attribute__((address_space(3))) void*       las3_t;

__device__ __forceinline__ float b2f(unsigned short s) {
    return __uint_as_float(((unsigned)s) << 16);
}
__device__ __forceinline__ unsigned short f2b(float f) {
    unsigned u = __float_as_uint(f);
    u += 0x7fffu + ((u >> 16) & 1u);   // RNE
    return (unsigned short)(u >> 16);
}

// HW packed f32->bf16 convert (1 instr for 2 elems vs 4 VALU ops each).
// GEMM2 A-path only; absmax bit-identical (7.63e-6) across R16-R20.
__device__ __forceinline__ unsigned cvt_pk_bf16(float lo, float hi) {
    unsigned r;
    asm("v_cvt_pk_bf16_f32 %0, %1, %2" : "=v"(r) : "v"(lo), "v"(hi));
    return r;
}

// LDS-only barrier: waits lgkmcnt(0) (all DS ops done) but does NOT drain
// vmcnt -- prefetched global loads stay in flight across the barrier.
// __syncthreads() would emit s_waitcnt vmcnt(0) lgkmcnt(0) and neutralize
// the register prefetch every iteration (R20 post-mortem). Single asm block
// so nothing can be scheduled between the wait and the barrier; "memory"
// clobber orders all memory ops across it.
__device__ __forceinline__ void lds_barrier() {
    asm volatile("s_waitcnt lgkmcnt(0)\n\ts_barrier" ::: "memory");
}

// LDS swizzle for BK=32 (64B rows, 4x16B slots): slot' = slot ^ ((row>>1)&3)
// -> ds_read_b128 fragment reads are 2-way (free, m136) instead of 8-way.
__device__ __forceinline__ int swz(int row, int slot) {
    return slot ^ ((row >> 1) & 3);
}

// ---------------------------------------------------------------------------
// Transpose + cast f32 [R,C] -> bf16 [C,R]
__global__ void k_transpose_cast(const float* __restrict__ in,
                                 unsigned short* __restrict__ out,
                                 int R, int C) {
    __shared__ float tile[32][33];
    const int c0 = blockIdx.x * 32, r0 = blockIdx.y * 32;
    const int tx = threadIdx.x & 31, ty = threadIdx.x >> 5;  // ty 0..7
#pragma unroll
    for (int j = 0; j < 4; ++j)
        tile[ty * 4 + j][tx] = in[(size_t)(r0 + ty * 4 + j) * C + c0 + tx];
    __syncthreads();
#pragma unroll
    for (int j = 0; j < 4; ++j)
        out[(size_t)(c0 + ty * 4 + j) * R + r0 + tx] = f2b(tile[tx][ty * 4 + j]);
}

// ---------------------------------------------------------------------------
// Cast f32 -> bf16, 4 elems/thread.
__global__ void k_cast_bf16(const float* __restrict__ in,
                            unsigned short* __restrict__ out, int n4) {
    int i = blockIdx.x * blockDim.x + threadIdx.x;
    if (i < n4) {
        float4 v = ((const float4*)in)[i];
        ushort4 o;
        o.x = f2b(v.x); o.y = f2b(v.y); o.z = f2b(v.z); o.w = f2b(v.w);
        ((ushort4*)out)[i] = o;
    }
}

// ---------------------------------------------------------------------------
// GEMM1 (R10 proven): h[M,N] = A[M,K] * Bt[N,K]^T, bf16 out + fused col stats.
// BM=BN=128, BK=32, swizzled global_load_lds staging. grid (N/128, M/128).
__global__ __launch_bounds__(256) void k_gemm1(
    const unsigned short* __restrict__ A, const unsigned short* __restrict__ Bt,
    unsigned short* __restrict__ Cout,
    float* __restrict__ cs, float* __restrict__ cs2,
    int M, int N, int K) {
    constexpr int BK = 32, BM = 128, BN = 128;
    constexpr int MI = 4, NI = 4;
    __shared__ __align__(16) short As[BM * BK];
    __shared__ __align__(16) short Bs[BN * BK];

    const int t = threadIdx.x;
    const int lane = t & 63, wv = t >> 6;
    const int wr = wv >> 1, wc = wv & 1;
    const int l15 = lane & 15, quad = lane >> 4;
    const int m0 = blockIdx.y * BM, n0 = blockIdx.x * BN;

    f32x4 acc[MI][NI] = {};

    for (int k0 = 0; k0 < K; k0 += BK) {
#pragma unroll
        for (int q = 0; q < 2; ++q) {
            int u = q * 256 + t;
            int row = u >> 2, kc = swz(row, u & 3);
            const short* gp = (const short*)A + (size_t)(m0 + row) * K + k0 + kc * 8;
            short* lp = As + (size_t)(q * 256 + (wv << 6)) * 8;  // wave-uniform base
            __builtin_amdgcn_global_load_lds((gas1_t)gp, (las3_t)lp, 16, 0, 0);
        }
#pragma unroll
        for (int q = 0; q < 2; ++q) {
            int u = q * 256 + t;
            int row = u >> 2, kc = swz(row, u & 3);
            const short* gp = (const short*)Bt + (size_t)(n0 + row) * K + k0 + kc * 8;
            short* lp = Bs + (size_t)(q * 256 + (wv << 6)) * 8;
            __builtin_amdgcn_global_load_lds((gas1_t)gp, (las3_t)lp, 16, 0, 0);
        }
        __syncthreads();

        short8 af[MI], bfr[NI];
#pragma unroll
        for (int mi = 0; mi < MI; ++mi) {
            int row = wr * 64 + mi * 16 + l15;
            af[mi] = *(const short8*)(As + row * BK + (swz(row, quad) << 3));
        }
#pragma unroll
        for (int ni = 0; ni < NI; ++ni) {
            int row = wc * 64 + ni * 16 + l15;
            bfr[ni] = *(const short8*)(Bs + row * BK + (swz(row, quad) << 3));
        }
#pragma unroll
        for (int mi = 0; mi < MI; ++mi)
#pragma unroll
            for (int ni = 0; ni < NI; ++ni)
                acc[mi][ni] = __builtin_amdgcn_mfma_f32_16x16x32_bf16(
                    af[mi], bfr[ni], acc[mi][ni], 0, 0, 0);
        __syncthreads();
    }

    // epilogue: C/D layout col=lane&15, row=quad*4+reg (measured m89)
#pragma unroll
    for (int ni = 0; ni < NI; ++ni) {
        float s = 0.f, s2 = 0.f;
#pragma unroll
        for (int mi = 0; mi < MI; ++mi)
#pragma unroll
            for (int r = 0; r < 4; ++r) {
                int row = m0 + wr * 64 + mi * 16 + quad * 4 + r;
                int col = n0 + wc * 64 + ni * 16 + l15;
                float v = acc[mi][ni][r];
                Cout[(size_t)row * N + col] = f2b(v);
                s += v; s2 += v * v;
            }
        s  += __shfl_xor(s, 16);  s  += __shfl_xor(s, 32);
        s2 += __shfl_xor(s2, 16); s2 += __shfl_xor(s2, 32);
        if (quad == 0) {
            int col = n0 + wc * 64 + ni * 16 + l15;
            atomicAdd(&cs[col], s);
            atomicAdd(&cs2[col], s2);
        }
    }
}

// BN scale/shift packed as bf16 pair: ssb[k] = f2b(scale)<<16 | f2b(shift)
// (bf16 params verified numerically R6/R9/R10/R14: absmax 7.6e-6 vs 2e-5 thr)
__global__ void k_bnprep(const float* __restrict__ sum, const float* __restrict__ sumsq,
                         const float* __restrict__ gamma, const float* __restrict__ beta,
                         unsigned* __restrict__ ssb) {
    int j = blockIdx.x * 256 + threadIdx.x;
    float mu = sum[j] * (1.f / B_ROWS);
    float var = sumsq[j] * (1.f / B_ROWS) - mu * mu;
    float sc = gamma[j] * rsqrtf(var + 1e-5f);
    float sh = beta[j] - mu * sc;
    ssb[j] = ((unsigned)f2b(sc) << 16) | (unsigned)f2b(sh);
}

__device__ __forceinline__ short8 bnrelu8(uint4 hv, uint4 sa, uint4 sb) {
    const unsigned short* hu = (const unsigned short*)&hv;
    const unsigned* wa = (const unsigned*)&sa;
    const unsigned* wb = (const unsigned*)&sb;
    float f[8];
#pragma unroll
    for (int j = 0; j < 8; ++j) {
        unsigned w = j < 4 ? wa[j] : wb[j - 4];
        float sc = __uint_as_float(w & 0xffff0000u);
        float sh = __uint_as_float(w << 16);
        f[j] = fmaxf(b2f(hu[j]) * sc + sh, 0.f);
    }
    union { unsigned u[4]; short8 s; } o;
#pragma unroll
    for (int j = 0; j < 4; ++j) o.u[j] = cvt_pk_bf16(f[2 * j], f[2 * j + 1]);
    return o.s;
}

// ---------------------------------------------------------------------------
// GEMM2 (R21): R20 geometry (BM=32, 8 blocks/CU, 32 waves/CU) with ONE change:
// the per-iter __syncthreads (which emits s_waitcnt vmcnt(0) -> drains the
// register prefetch EVERY iteration, R20 post-mortem) is replaced by
// lds_barrier() = inline "s_waitcnt lgkmcnt(0); s_barrier". Global prefetch
// loads now stay in flight across the barrier; vmcnt waits happen at their
// use one iteration later (T4 counted-vmcnt mechanism). Double-buffer
// correctness unchanged: lgkmcnt(0) still orders all LDS writes AND the
// prior-iter reads before each barrier.
__global__ __launch_bounds__(256, 8) void k_gemm2d(
    const unsigned short* __restrict__ A, const unsigned short* __restrict__ Bt,
    float* __restrict__ Cout, const float* __restrict__ bias,
    const unsigned* __restrict__ ssb,
    int M, int N, int K) {
    constexpr int BK = 32, BM = 32, BN = 128;
    constexpr int NI = 4;
    __shared__ __align__(16) short As[2][BM * BK];   // 2 x 2 KB
    __shared__ __align__(16) short Bs[2][BN * BK];   // 2 x 8 KB

    const int t = threadIdx.x;
    const int lane = t & 63, wv = t >> 6;
    const int wr = wv >> 1, wc = wv & 1;             // 2x2 wave grid, tile 16x64
    const int l15 = lane & 15, quad = lane >> 4;
    const int m0 = blockIdx.y * BM, n0 = blockIdx.x * BN;

    const int Kc = K / gridDim.z;
    const int kbeg = blockIdx.z * Kc;
    const int ITERS = Kc / BK;

    const bool aw = (t < 128);                       // waves 0-1 stage A
    const int arow = (t & 127) >> 2, akc = t & 3;    // A: 32 rows x 4 slots
    const unsigned short* hp = A + (size_t)(m0 + arow) * K + akc * 8;
    const unsigned* ssp = ssb + akc * 8;
    const int awoff = arow * BK + (swz(arow, akc) << 3);

    const int brow = t >> 2;                         // B: rows 0..63 (+64)
    const unsigned short* bp0 = Bt + (size_t)(n0 + brow) * K + akc * 8;
    const unsigned short* bp1 = Bt + (size_t)(n0 + 64 + brow) * K + akc * 8;
    const int bwoff0 = brow * BK + (swz(brow, akc) << 3);
    const int bwoff1 = (64 + brow) * BK + (swz(64 + brow, akc) << 3);

    f32x4 acc[NI] = {};

    uint4 hreg = {}, sa = {}, sb = {};
    if (aw) {
        hreg = *(const uint4*)(hp + kbeg);
        sa = *(const uint4*)(ssp + kbeg);
        sb = *(const uint4*)(ssp + kbeg + 4);
    }
    uint4 b0 = *(const uint4*)(bp0 + kbeg);
    uint4 b1 = *(const uint4*)(bp1 + kbeg);

    for (int i = 0; i < ITERS; ++i) {
        const int k0 = kbeg + i * BK;
        short* Ab = As[i & 1];
        short* Bb = Bs[i & 1];

        if (aw) *(short8*)(Ab + awoff) = bnrelu8(hreg, sa, sb);
        *(uint4*)(Bb + bwoff0) = b0;
        *(uint4*)(Bb + bwoff1) = b1;
        lds_barrier();   // lgkm-only: prefetch loads stay in flight

        const int kn = (i + 1 < ITERS) ? k0 + BK : kbeg;
        if (aw) {
            hreg = *(const uint4*)(hp + kn);
            sa = *(const uint4*)(ssp + kn);
            sb = *(const uint4*)(ssp + kn + 4);
        }
        b0 = *(const uint4*)(bp0 + kn);
        b1 = *(const uint4*)(bp1 + kn);

        short8 af, bfr[NI];
        {
            int row = wr * 16 + l15;
            af = *(const short8*)(Ab + row * BK + (swz(row, quad) << 3));
        }
#pragma unroll
        for (int ni = 0; ni < NI; ++ni) {
            int row = wc * 64 + ni * 16 + l15;
            bfr[ni] = *(const short8*)(Bb + row * BK + (swz(row, quad) << 3));
        }
#pragma unroll
        for (int ni = 0; ni < NI; ++ni)
            acc[ni] = __builtin_amdgcn_mfma_f32_16x16x32_bf16(
                af, bfr[ni], acc[ni], 0, 0, 0);
    }

#pragma unroll
    for (int ni = 0; ni < NI; ++ni)
#pragma unroll
        for (int r = 0; r < 4; ++r) {
            int row = m0 + wr * 16 + quad * 4 + r;
            int col = n0 + wc * 64 + ni * 16 + l15;
            float v = acc[ni][r];
            if (blockIdx.z == 0) v += bias[col];
            atomicAdd(&Cout[(size_t)row * N + col], v);
        }
}

// ---------------------------------------------------------------------------
// Fused norm + transpose + cast (R14-proven): per 32-row slab of X [8192,256]
// f32: load to LDS, row inv-norms, write XT [256,8192] bf16 normalized.
// grid (B/32, 4), block 256.
__global__ __launch_bounds__(256) void k_ntc(
    const float* __restrict__ x0, const float* __restrict__ x1,
    const float* __restrict__ x2, const float* __restrict__ x3,
    unsigned short* __restrict__ o0, unsigned short* __restrict__ o1,
    unsigned short* __restrict__ o2, unsigned short* __restrict__ o3) {
    const int z = blockIdx.y;
    const float* x = z == 0 ? x0 : z == 1 ? x1 : z == 2 ? x2 : x3;
    unsigned short* out = z == 0 ? o0 : z == 1 ? o1 : z == 2 ? o2 : o3;

    __shared__ float tile[32][264];
    __shared__ float red[32][8];
    __shared__ float invs[32];
    const int t = threadIdx.x;
    const int r0 = blockIdx.x * 32;

#pragma unroll
    for (int i = 0; i < 8; ++i) {
        int u = i * 256 + t;
        int row = u >> 6, cp = (u & 63) * 4;
        float4 v = *(const float4*)(x + (size_t)(r0 + row) * E_DIM + cp);
        *(float4*)&tile[row][cp] = v;
    }
    __syncthreads();
    {
        int row = t >> 3, cg = (t & 7) * 32;
        float s = 0.f;
#pragma unroll
        for (int j = 0; j < 32; ++j) { float v = tile[row][cg + j]; s += v * v; }
        red[row][t & 7] = s;
    }
    __syncthreads();
    if (t < 32) {
        float s = 0.f;
#pragma unroll
        for (int j = 0; j < 8; ++j) s += red[t][j];
        invs[t] = 1.f / fmaxf(sqrtf(s), 1e-12f);
    }
    __syncthreads();
    {
        int row = t & 31, cb = (t >> 5) * 32;
        float inv = invs[row];
#pragma unroll
        for (int j = 0; j < 32; ++j) {
            int c = cb + j;
            out[(size_t)c * B_ROWS + r0 + row] = f2b(tile[row][c] * inv);
        }
    }
}

// ---------------------------------------------------------------------------
// Gram via MFMA: Mout[a,b] += sum_k AT[a,k]*BT[b,k], AT/BT bf16 [256,8192].
// BM=BN=64, BK=32, swizzled staging, split-K x16; grid (4,4,32).
#define GKS 16
__global__ __launch_bounds__(256) void k_gram(
    const unsigned short* __restrict__ p1T, const unsigned short* __restrict__ q2T,
    const unsigned short* __restrict__ p2T, const unsigned short* __restrict__ q1T,
    float* __restrict__ Ma, float* __restrict__ Mb) {
    constexpr int BK = 32;
    const int mec = blockIdx.z >> 4, kz = blockIdx.z & 15;
    const unsigned short* A = mec ? p2T : p1T;
    const unsigned short* Bt = mec ? q1T : q2T;
    float* Mout = mec ? Mb : Ma;

    __shared__ __align__(16) short As[64 * BK];
    __shared__ __align__(16) short Bs[64 * BK];

    const int t = threadIdx.x;
    const int lane = t & 63, wv = t >> 6;
    const int wr = wv >> 1, wc = wv & 1;
    const int l15 = lane & 15, quad = lane >> 4;
    const int m0 = blockIdx.y * 64, n0 = blockIdx.x * 64;
    const int kbeg = kz * (B_ROWS / GKS);

    f32x4 acc[2][2] = {};

    for (int k0 = kbeg; k0 < kbeg + B_ROWS / GKS; k0 += BK) {
        {
            int row = t >> 2, kc = swz(row, t & 3);
            const short* gpa = (const short*)A + (size_t)(m0 + row) * B_ROWS + k0 + kc * 8;
            short* lpa = As + (size_t)(wv << 6) * 8;
            __builtin_amdgcn_global_load_lds((gas1_t)gpa, (las3_t)lpa, 16, 0, 0);
            const short* gpb = (const short*)Bt + (size_t)(n0 + row) * B_ROWS + k0 + kc * 8;
            short* lpb = Bs + (size_t)(wv << 6) * 8;
            __builtin_amdgcn_global_load_lds((gas1_t)gpb, (las3_t)lpb, 16, 0, 0);
        }
        __syncthreads();

        short8 af[2], bfr[2];
#pragma unroll
        for (int mi = 0; mi < 2; ++mi) {
            int row = wr * 32 + mi * 16 + l15;
            af[mi] = *(const short8*)(As + row * BK + (swz(row, quad) << 3));
        }
#pragma unroll
        for (int ni = 0; ni < 2; ++ni) {
            int row = wc * 32 + ni * 16 + l15;
            bfr[ni] = *(const short8*)(Bs + row * BK + (swz(row, quad) << 3));
        }
#pragma unroll
        for (int mi = 0; mi < 2; ++mi)
#pragma unroll
            for (int ni = 0; ni < 2; ++ni)
                acc[mi][ni] = __builtin_amdgcn_mfma_f32_16x16x32_bf16(
                    af[mi], bfr[ni], acc[mi][ni], 0, 0, 0);
        __syncthreads();
    }

#pragma unroll
    for (int mi = 0; mi < 2; ++mi)
#pragma unroll
        for (int ni = 0; ni < 2; ++ni)
#pragma unroll
            for (int r = 0; r < 4; ++r) {
                int row = m0 + wr * 32 + mi * 16 + quad * 4 + r;
                int col = n0 + wc * 32 + ni * 16 + l15;
                atomicAdd(&Mout[(size_t)row * E_DIM + col], acc[mi][ni][r]);
            }
}

// M2 = M*M (256x256). grid (16,16,2) block 256.
__global__ void k_m2(const float* __restrict__ Ma, const float* __restrict__ Mb,
                     float* __restrict__ M2a, float* __restrict__ M2b) {
    const float* M = blockIdx.z ? Mb : Ma;
    float* M2 = blockIdx.z ? M2b : M2a;
    int b = blockIdx.x * 16 + (threadIdx.x & 15);
    int a = blockIdx.y * 16 + (threadIdx.x >> 4);
    float s = 0.f;
    for (int k = 0; k < E_DIM; ++k) s += M[a * E_DIM + k] * M[k * E_DIM + b];
    M2[a * E_DIM + b] = s;
}

// ---------------------------------------------------------------------------
// Traces, tiled multi-block: grid (8,8,2), block 256.
__global__ __launch_bounds__(256) void k_traces2(
    const float* __restrict__ Ma, const float* __restrict__ M2a,
    const float* __restrict__ Mb, const float* __restrict__ M2b,
    const float* __restrict__ lam, float* __restrict__ out) {
    const float* M  = blockIdx.z ? Mb  : Ma;
    const float* M2 = blockIdx.z ? M2b : M2a;
    const int i0 = blockIdx.y * 32, j0 = blockIdx.x * 32;
    const int t = threadIdx.x, col = t & 31, row = t >> 5;  // row 0..7

    __shared__ float A[32][33], Bt[32][33], A2[32][33], B2[32][33];
#pragma unroll
    for (int r = 0; r < 4; ++r) {
        int rr = r * 8 + row;
        A [rr][col] = M [(i0 + rr) * E_DIM + j0 + col];
        Bt[rr][col] = M [(j0 + rr) * E_DIM + i0 + col];
        A2[rr][col] = M2[(i0 + rr) * E_DIM + j0 + col];
        B2[rr][col] = M2[(j0 + rr) * E_DIM + i0 + col];
    }
    __syncthreads();

    float lamv = lam[0];
    float il = 1.f / lamv;
    float F = -0.5f * lamv * (1.f / B_ROWS);  // -0.5*lam/B
    float c1 = F * il;
    float c2 = -F * 0.5f * il * il;
    float c3 = F * (1.f / 3.f) * il * il * il;
    float c4 = -F * 0.25f * il * il * il * il;

    float s = 0.f;
#pragma unroll
    for (int r = 0; r < 4; ++r) {
        int rr = r * 8 + row;
        float mij = A[rr][col], mji = Bt[col][rr];
        float m2ij = A2[rr][col], m2ji = B2[col][rr];
        s += c2 * mij * mji + c3 * m2ij * mji + c4 * m2ij * m2ji;
        if (i0 + rr == j0 + col) s += c1 * mij;
    }
#pragma unroll
    for (int o = 32; o; o >>= 1) s += __shfl_down(s, o);
    __shared__ float red[4];
    if ((t & 63) == 0) red[t >> 6] = s;
    __syncthreads();
    if (t == 0) atomicAdd(out, red[0] + red[1] + red[2] + red[3]);
}

// ---------------------------------------------------------------------------
extern "C" void kernel_launch(void* const* d_in, const int* in_sizes, int n_in,
                              void* d_out, int out_size, void* d_ws, size_t ws_size,
                              hipStream_t stream) {
    const float* z1 = (const float*)d_in[0];
    const float* z2 = (const float*)d_in[1];
    const float* p1 = (const float*)d_in[2];
    const float* p2 = (const float*)d_in[3];
    const float* W1 = (const float*)d_in[4];
    const float* gamma = (const float*)d_in[5];
    const float* beta = (const float*)d_in[6];
    const float* W2 = (const float*)d_in[7];
    const float* b2 = (const float*)d_in[8];
    const float* lam = (const float*)d_in[9];
    float* out = (float*)d_out;
    char* ws = (char*)d_ws;

    // workspace layout (~89 MB)
    size_t off = 0;
    auto alloc = [&](size_t bytes) { size_t o = off; off += (bytes + 255) & ~(size_t)255; return o; };
    unsigned short* W1T = (unsigned short*)(ws + alloc((size_t)E_DIM * H_DIM * 2));  // [H,E] bf16
    unsigned short* W2T = (unsigned short*)(ws + alloc((size_t)H_DIM * E_DIM * 2));  // [E,H] bf16
    unsigned short* zb  = (unsigned short*)(ws + alloc((size_t)B_ROWS * E_DIM * 2));
    unsigned short* h   = (unsigned short*)(ws + alloc((size_t)B_ROWS * H_DIM * 2));
    // q1,q2,Ma,Mb contiguous -> single memset
    float* q1 = (float*)(ws + alloc((size_t)B_ROWS * E_DIM * 4));
    float* q2 = (float*)(ws + alloc((size_t)B_ROWS * E_DIM * 4));
    float* Ma  = (float*)(ws + alloc((size_t)E_DIM * E_DIM * 4));
    float* Mb  = (float*)(ws + alloc((size_t)E_DIM * E_DIM * 4));
    float* M2a = (float*)(ws + alloc((size_t)E_DIM * E_DIM * 4));
    float* M2b = (float*)(ws + alloc((size_t)E_DIM * E_DIM * 4));
    // two colsum sets (one per view), contiguous -> single memset
    float* cs0 = (float*)(ws + alloc(H_DIM * 4));
    float* cs0q = (float*)(ws + alloc(H_DIM * 4));
    float* cs1 = (float*)(ws + alloc(H_DIM * 4));
    float* cs1q = (float*)(ws + alloc(H_DIM * 4));
    unsigned* ssb = (unsigned*)(ws + alloc(H_DIM * 4));

    // transposed normalized bf16 views alias into h (free after last GEMM2)
    const size_t TSZ = (size_t)E_DIM * B_ROWS;  // 2M elements each
    unsigned short* p1T = h;
    unsigned short* q2T = h + TSZ;
    unsigned short* p2T = h + 2 * TSZ;
    unsigned short* q1T = h + 3 * TSZ;

    // zero accumulation targets (3 memsets total)
    hipMemsetAsync(out, 0, sizeof(float), stream);
    hipMemsetAsync(q1, 0, ((size_t)2 * B_ROWS * E_DIM + 2 * E_DIM * E_DIM) * 4, stream);
    hipMemsetAsync(cs0, 0, (size_t)4 * H_DIM * 4, stream);

    // weight transposes (k-contiguous operands for MFMA)
    k_transpose_cast<<<dim3(H_DIM / 32, E_DIM / 32), 256, 0, stream>>>(W1, W1T, E_DIM, H_DIM);
    k_transpose_cast<<<dim3(E_DIM / 32, H_DIM / 32), 256, 0, stream>>>(W2, W2T, H_DIM, E_DIM);

    const float* zs[2] = {z1, z2};
    float* qs[2] = {q1, q2};
    float* css[2] = {cs0, cs1};
    float* cssq[2] = {cs0q, cs1q};
    for (int v = 0; v < 2; ++v) {
        k_cast_bf16<<<dim3(B_ROWS * E_DIM / 4 / 256), 256, 0, stream>>>(zs[v], zb, B_ROWS * E_DIM / 4);
        // h = z @ W1, with fused column stats
        k_gemm1<<<dim3(H_DIM / 128, B_ROWS / 128), 256, 0, stream>>>(
            zb, W1T, h, css[v], cssq[v], B_ROWS, H_DIM, E_DIM);
        k_bnprep<<<dim3(H_DIM / 256), 256, 0, stream>>>(css[v], cssq[v], gamma, beta, ssb);
        // q = relu(bn(h)) @ W2 + b2 — R20 geometry + lgkm-only barrier, split-K x4
        k_gemm2d<<<dim3(E_DIM / 128, B_ROWS / 32, 4), 256, 0, stream>>>(
            h, W2T, qs[v], b2, ssb, B_ROWS, E_DIM, H_DIM);
    }

    // fused row-norm + transpose + cast of p1,q2,p2,q1 (into h's space)
    k_ntc<<<dim3(B_ROWS / 32, 4), 256, 0, stream>>>(
        p1, q2, p2, q1, p1T, q2T, p2T, q1T);

    k_gram<<<dim3(4, 4, 2 * GKS), 256, 0, stream>>>(p1T, q2T, p2T, q1T, Ma, Mb);
    k_m2<<<dim3(16, 16, 2), 256, 0, stream>>>(Ma, Mb, M2a, M2b);
    k_traces2<<<dim3(8, 8, 2), 256, 0, stream>>>(Ma, M2a, Mb, M2b, lam, out);
}